// Round 12
// baseline (250.293 us; speedup 1.0000x reference)
//
#include <hip/hip_runtime.h>
#include <math.h>

#define NN 20
#define FF 128
#define TT 100
#define EE 128
#define KD 356

typedef unsigned int u32;
typedef unsigned short u16;
typedef unsigned long long u64;
typedef __attribute__((ext_vector_type(4))) float f32x4;
typedef __attribute__((ext_vector_type(8))) short s16x8;
typedef __attribute__((ext_vector_type(4))) u32 u32x4;

__device__ __forceinline__ u16 f2b(float f) {
    u32 u = __float_as_uint(f);
    u32 r = u + 0x7FFFu + ((u >> 16) & 1u);   // RNE
    return (u16)(r >> 16);
}
__device__ __forceinline__ float b2f(u16 h) { return __uint_as_float(((u32)h) << 16); }
__device__ __forceinline__ float blo(u32 u){ return __uint_as_float(u << 16); }
__device__ __forceinline__ float bhi(u32 u){ return __uint_as_float(u & 0xFFFF0000u); }
__device__ __forceinline__ u32 pk2(float a, float b){ return (u32)f2b(a) | ((u32)f2b(b) << 16); }
__device__ __forceinline__ u32 cvtpk(float a, float b){
    u32 d; asm("v_cvt_pk_bf16_f32 %0, %1, %2" : "=v"(d) : "v"(a), "v"(b)); return d;
}
__device__ __forceinline__ void lgkm_barrier() {
    asm volatile("s_waitcnt lgkmcnt(0)" ::: "memory");
    __builtin_amdgcn_s_barrier();
    asm volatile("" ::: "memory");
}

// ==================== tier-1 fast path ====================

__global__ void prep_fuse(const float* __restrict__ Wt, const float* __restrict__ bt,
                          const float* __restrict__ Wk, const float* __restrict__ Wv,
                          const u32* __restrict__ maskw,
                          float* __restrict__ wkt, float* __restrict__ wvt,
                          float* __restrict__ kfb, float* __restrict__ vfb, int* __restrict__ flagp)
{
    const int blk = blockIdx.x, t = threadIdx.x;  // 128 threads
    if (blk < KD) {
        __shared__ float col[FF];
        col[t] = Wt[t * KD + blk];
        __syncthreads();
        float ak = 0.f, av = 0.f;
        for (int j = 0; j < FF; ++j) {
            float c = col[j];
            ak = fmaf(Wk[t * FF + j], c, ak);
            av = fmaf(Wv[t * FF + j], c, av);
        }
        wkt[blk * FF + t] = ak;
        wvt[blk * FF + t] = av;
    } else if (blk == KD) {
        float ak = 0.f, av = 0.f;
        for (int j = 0; j < FF; ++j) {
            float c = bt[j];
            ak = fmaf(Wk[t * FF + j], c, ak);
            av = fmaf(Wv[t * FF + j], c, av);
        }
        kfb[t] = ak; vfb[t] = av;
    } else {
        int any = 0;
        for (int i = t; i < 8192; i += 128) any |= (maskw[i] > 1u) ? 1 : 0;
        any = __any(any) ? 1 : 0;
        __shared__ int red[2];
        if ((t & 63) == 0) red[t >> 6] = any;
        __syncthreads();
        if (t == 0) *flagp = (red[0] | red[1]) ? 1 : 0;
    }
}

// prep2 v4: fragment-major B image + padded LDS images for small GEMMs.
__global__ void prep_pack_v4(const float* __restrict__ wkt, const float* __restrict__ wvt,
                             const float* __restrict__ Wq, const float* __restrict__ Wo,
                             const float* __restrict__ W1, const float* __restrict__ W2,
                             u16* __restrict__ kvB, u16* __restrict__ wqI, u16* __restrict__ woI,
                             u16* __restrict__ w1I, u16* __restrict__ w2I)
{
    const int id = blockIdx.x * 256 + threadIdx.x;   // 1128*256 = 288768
    if (id < 196608) {
        int chunk = id >> 9, e = id & 511;
        int ln = e >> 3, ee = e & 7;
        int kt = chunk >> 4, nb = chunk & 15;
        int k = kt * 32 + (ln >> 4) * 8 + ee;
        int n = nb * 16 + (ln & 15);
        float v = 0.f;
        if (k < KD) v = (n < FF) ? wkt[k * FF + n] : wvt[k * FF + (n - FF)];
        kvB[id] = f2b(v);
    } else if (id < 215040) {
        int e = id - 196608; int rem = e % 9216;
        int n = rem / 72, kk = rem % 72; int k = (e / 9216) * 64 + kk;
        wqI[e] = f2b(kk < 64 ? Wq[n * FF + k] : 0.f);
    } else if (id < 233472) {
        int e = id - 215040; int rem = e % 9216;
        int n = rem / 72, kk = rem % 72; int k = (e / 9216) * 64 + kk;
        woI[e] = f2b(kk < 64 ? Wo[n * FF + k] : 0.f);
    } else if (id < 270336) {
        int e = id - 233472; int rem = e % 9216;
        int n = rem / 72, kk = rem % 72; int k = (e / 9216) * 64 + kk;
        w1I[e] = f2b(kk < 64 ? W1[n * 2 * FF + k] : 0.f);
    } else if (id < 288768) {
        int e = id - 270336; int rem = e % 9216;
        int n = rem / 72, kk = rem % 72; int k = (e / 9216) * 64 + kk;
        w2I[e] = f2b(kk < 64 ? W2[n * FF + k] : 0.f);
    }
}

// FUSED v8: fused7 GEMM schedule, persistent over NG groups per block.
// kls gets its OWN region (no alias with A-ring) so next-group prefetch is issued
// BEFORE the attention phases and overlaps them; attention barriers are lgkm-only
// (no vmcnt drain). Counted vmcnt stays safe: attention ops are younger than our
// staged chunks, so they only add to (never subtract from) the outstanding count.
template<int NG>
__global__ __launch_bounds__(512) void kv_attn_fused8(
    const float* __restrict__ nbr, const float* __restrict__ edg, const float* __restrict__ tmf,
    const float* __restrict__ wgt, const float* __restrict__ bk, const float* __restrict__ bv,
    const u16* __restrict__ kvB, const float* __restrict__ kfb, const float* __restrict__ vfb,
    const u16* __restrict__ Qg, const void* __restrict__ maskp, const int* __restrict__ flagp,
    u16* __restrict__ ctxout, unsigned char* __restrict__ flags)
{
    __shared__ __align__(16) u16 smem[26240];   // 52480B: A ring 3x10240 | kls 21120 | p 640
    char* sb = (char*)smem;
    u16* kls = (u16*)(sb + 30720);
    float* p_lds = (float*)(sb + 51840);

    const int tid = threadIdx.x;
    const int lane = tid & 63, wave = tid >> 6;  // 8 waves
    const int wn = wave;
    const int kg = lane >> 4, l16 = lane & 15;
    const int rg4 = (lane >> 4) * 4;
    const int lb = wave >> 1, h = wave & 1;
    const int flagv = *flagp;

    int Mbase = blockIdx.x * NG * 80;

    f32x4 acc[5][2];
    s16x8 br[2][2];
    f32x4 tl[5];

    #define STAGE_CHUNK(C, KT, MB) do {                                                     \
        int row_ = (C) * 8 + (lane >> 3);                                                   \
        int x_ = (lane & 7) ^ (row_ & 7);                                                   \
        const float* g_;                                                                    \
        if ((KT) < 4)      g_ = nbr + (size_t)((MB) + row_) * 128 + (KT) * 32 + x_ * 4;     \
        else if ((KT) < 8) g_ = edg + (size_t)((MB) + row_) * 128 + ((KT)-4) * 32 + x_ * 4; \
        else               g_ = tmf + (size_t)((MB) + row_) * 100 + ((KT)-8) * 32 + x_ * 4; \
        __builtin_amdgcn_global_load_lds((const __attribute__((address_space(1))) u32*)g_,  \
            (__attribute__((address_space(3))) u32*)(sb + ((KT)%3)*10240 + (C)*1024), 16, 0, 0); \
    } while (0)

    #define STAGE(KT, MB) do {                                                              \
        STAGE_CHUNK(wave, KT, MB);                                                          \
        if (wave < 2) STAGE_CHUNK(8 + wave, KT, MB);                                        \
    } while (0)

    #define LOADB(KT) do {                                                                  \
        br[(KT)&1][0] = *(const s16x8*)(kvB + (size_t)((KT)*16 + wn*2 + 0)*512 + lane*8);   \
        br[(KT)&1][1] = *(const s16x8*)(kvB + (size_t)((KT)*16 + wn*2 + 1)*512 + lane*8);   \
    } while (0)

    #define PREFETCH(MB) do {                                                               \
        _Pragma("unroll")                                                                   \
        for (int mt_ = 0; mt_ < 5; ++mt_)                                                   \
            tl[mt_] = *(const f32x4*)(tmf + (size_t)((MB) + mt_ * 16 + l16) * 100 + 96);    \
        STAGE(0, MB); STAGE(1, MB); STAGE(2, MB);                                           \
        LOADB(0); LOADB(1);                                                                 \
    } while (0)

    #define NV1(KT) ((KT)==0?6:((KT)==1?8:((KT)==2?10:((KT)<=8?8:((KT)==9?7:6)))))
    #define NV2(KT) ((KT)==0?8:((KT)==1?10:((KT)==2?12:((KT)<=8?10:((KT)==9?8:6)))))

    #define GITER(KT) do {                                                                  \
        if ((KT) <= 10) {                                                                   \
            if (wave < 2) { asm volatile("s_waitcnt vmcnt(%0)" :: "i"(NV2(KT)) : "memory"); }\
            else          { asm volatile("s_waitcnt vmcnt(%0)" :: "i"(NV1(KT)) : "memory"); }\
            __builtin_amdgcn_s_barrier();                                                   \
            __builtin_amdgcn_sched_barrier(0);                                              \
        }                                                                                   \
        s16x8 af[5];                                                                        \
        _Pragma("unroll")                                                                   \
        for (int mt = 0; mt < 5; ++mt) {                                                    \
            f32x4 lo, hi;                                                                   \
            if ((KT) <= 10) {                                                               \
                int r_ = mt * 16 + l16; int sw_ = r_ & 7; int y0_ = kg * 2;                 \
                const char* bp_ = sb + ((KT)%3)*10240 + r_ * 128;                           \
                lo = *(const f32x4*)(bp_ + ((y0_ ^ sw_) << 4));                             \
                hi = *(const f32x4*)(bp_ + (((y0_+1) ^ sw_) << 4));                         \
            } else {                                                                        \
                lo = (kg == 0) ? tl[mt] : (f32x4){0.f,0.f,0.f,0.f};                         \
                hi = (f32x4){0.f,0.f,0.f,0.f};                                              \
            }                                                                               \
            u32x4 q_;                                                                       \
            q_.x = cvtpk(lo.x, lo.y); q_.y = cvtpk(lo.z, lo.w);                             \
            q_.z = cvtpk(hi.x, hi.y); q_.w = cvtpk(hi.z, hi.w);                             \
            af[mt] = __builtin_bit_cast(s16x8, q_);                                         \
        }                                                                                   \
        _Pragma("unroll")                                                                   \
        for (int mt = 0; mt < 5; ++mt) {                                                    \
            acc[mt][0] = __builtin_amdgcn_mfma_f32_16x16x32_bf16(af[mt], br[(KT)&1][0], acc[mt][0], 0, 0, 0); \
            acc[mt][1] = __builtin_amdgcn_mfma_f32_16x16x32_bf16(af[mt], br[(KT)&1][1], acc[mt][1], 0, 0, 0); \
        }                                                                                   \
        if ((KT) <= 10) {                                                                   \
            asm volatile("s_waitcnt lgkmcnt(0)" ::: "memory");                              \
            __builtin_amdgcn_s_barrier();                                                   \
            __builtin_amdgcn_sched_barrier(0);                                              \
            if ((KT) <= 7) STAGE((KT)+3, Mbase);                                            \
            if ((KT)+2 <= 11) LOADB((KT)+2);                                                \
        }                                                                                   \
    } while (0)

    PREFETCH(Mbase);

    #pragma unroll 1
    for (int g = 0; g < NG; ++g) {
        #pragma unroll
        for (int mt = 0; mt < 5; ++mt) {
            acc[mt][0] = (f32x4){0.f,0.f,0.f,0.f};
            acc[mt][1] = (f32x4){0.f,0.f,0.f,0.f};
        }

        GITER(0); GITER(1); GITER(2);  GITER(3);
        GITER(4); GITER(5); GITER(6);  GITER(7);
        GITER(8); GITER(9); GITER(10); GITER(11);

        // issue next group's staging NOW — overlaps the attention phases below
        if (g + 1 < NG) PREFETCH(Mbase + 80);

        // ---- Phase A: epilogue. K waves -> kls; V waves keep acc in regs.
        if (wn < 4) {
            #pragma unroll
            for (int mt = 0; mt < 5; ++mt) {
                const int r0 = mt * 16 + rg4;
                float w4v[4];
                #pragma unroll
                for (int i = 0; i < 4; ++i) w4v[i] = wgt[Mbase + r0 + i];
                #pragma unroll
                for (int nt = 0; nt < 2; ++nt) {
                    const int c = wn * 32 + nt * 16 + l16;           // K col 0..127
                    const float fb = kfb[c], bb = bk[c];
                    #pragma unroll
                    for (int i = 0; i < 4; ++i)
                        kls[(r0 + i) * 132 + c] = f2b(fmaf(acc[mt][nt][i] + fb, w4v[i], bb));
                }
            }
        } else {
            #pragma unroll
            for (int mt = 0; mt < 5; ++mt) {
                const int r0 = mt * 16 + rg4;
                float w4v[4];
                #pragma unroll
                for (int i = 0; i < 4; ++i) w4v[i] = wgt[Mbase + r0 + i];
                #pragma unroll
                for (int nt = 0; nt < 2; ++nt) {
                    const int c = (wn - 4) * 32 + nt * 16 + l16;     // V col 0..127
                    const float fb = vfb[c], bb = bv[c];
                    #pragma unroll
                    for (int i = 0; i < 4; ++i)
                        acc[mt][nt][i] = fmaf(acc[mt][nt][i] + fb, w4v[i], bb);
                }
            }
        }
        lgkm_barrier();

        // ---- Phase B: scores + softmax; wave = (batch row lb, head h)
        const int brow = (blockIdx.x * NG + g) * 4 + lb;
        {
            bool mybit = false;
            if (lane < NN) {
                if (flagv) mybit = ((const unsigned char*)maskp)[brow * NN + lane] != 0;
                else       mybit = ((const int*)maskp)[brow * NN + lane] != 0;
            }
            u64 bal = __ballot(mybit);
            u32 mb = (u32)(bal & 0xFFFFFull);
            const bool invalid = (mb == 0xFFFFFu);
            if (invalid) mb &= ~1u;
            if (h == 0 && lane == 0) flags[brow] = invalid ? 1 : 0;

            const int n = lane & 31;
            float s = -INFINITY;
            if (lane < 32 && n < NN) {
                const u16* kr = kls + (lb * NN + n) * 132 + h * 64;
                const u16* qr = Qg + (size_t)brow * 128 + h * 64;
                float d = 0.f;
                #pragma unroll
                for (int dc = 0; dc < 16; ++dc) {
                    uint2 kw = *(const uint2*)(kr + dc * 4);
                    uint2 qw = *(const uint2*)(qr + dc * 4);
                    d = fmaf(blo(kw.x), blo(qw.x), d);  d = fmaf(bhi(kw.x), bhi(qw.x), d);
                    d = fmaf(blo(kw.y), blo(qw.y), d);  d = fmaf(bhi(kw.y), bhi(qw.y), d);
                }
                s = ((mb >> n) & 1u) ? -INFINITY : d * 0.125f;
            }
            float mx = s;
            #pragma unroll
            for (int off = 16; off; off >>= 1) mx = fmaxf(mx, __shfl_xor(mx, off, 32));
            float e = (lane < 32 && n < NN) ? expf(s - mx) : 0.f;
            float sum = e;
            #pragma unroll
            for (int off = 16; off; off >>= 1) sum += __shfl_xor(sum, off, 32);
            if (lane < NN) p_lds[wave * NN + lane] = e / sum;
        }
        lgkm_barrier();

        // ---- Phase C: V regs -> kls (overwrites K slots; reads done at barrier)
        if (wn >= 4) {
            #pragma unroll
            for (int mt = 0; mt < 5; ++mt) {
                const int r0 = mt * 16 + rg4;
                #pragma unroll
                for (int nt = 0; nt < 2; ++nt) {
                    const int c = (wn - 4) * 32 + nt * 16 + l16;
                    #pragma unroll
                    for (int i = 0; i < 4; ++i)
                        kls[(r0 + i) * 132 + c] = f2b(acc[mt][nt][i]);
                }
            }
        }
        lgkm_barrier();

        // ---- Phase D: ctx; wave = (lb,h), lane = d
        {
            float cacc = 0.f;
            #pragma unroll
            for (int n2 = 0; n2 < NN; ++n2) {
                float pn = p_lds[wave * NN + n2];
                cacc = fmaf(pn, b2f(kls[(lb * NN + n2) * 132 + h * 64 + lane]), cacc);
            }
            ctxout[(size_t)brow * 128 + h * 64 + lane] = f2b(cacc);
        }
        Mbase += 80;
        // next group's GITER(0) provides the vmcnt wait + barrier before kls reuse
    }
    #undef GITER
    #undef PREFETCH
    #undef STAGE
    #undef STAGE_CHUNK
    #undef LOADB
    #undef NV1
    #undef NV2
}

// generic small GEMM (used for Q only): C[M x 128] = A[M x 128] @ W^T + bias
#define GM_Q 0

template<int MODE>
__global__ __launch_bounds__(256) void gemm_small(
    const void* __restrict__ Asrc, const float* __restrict__ Asrc2,
    const u16* __restrict__ Bimg, const float* __restrict__ bias,
    const unsigned char* __restrict__ flags, void* __restrict__ outp)
{
    __shared__ u16 lA[64 * 72];
    __shared__ u16 lB[128 * 72];
    const int tid = threadIdx.x;
    const int Mbase = blockIdx.x * 64;
    const int lane = tid & 63, wave = tid >> 6;
    const int wm = wave >> 1, wn = wave & 1;
    const int row = tid >> 2, cg = tid & 3;

    f32x4 acc[2][4] = {};
    const size_t r = (size_t)(Mbase + row);

    for (int kt = 0; kt < 2; ++kt) {
        {
            const float* ap = (const float*)Asrc + r * 128 + kt * 64 + cg * 16;
            f32x4 x0 = *(const f32x4*)ap,       x1 = *(const f32x4*)(ap + 4);
            f32x4 x2 = *(const f32x4*)(ap + 8), x3 = *(const f32x4*)(ap + 12);
            *(uint4*)(&lA[row * 72 + cg * 16])     = make_uint4(pk2(x0.x,x0.y), pk2(x0.z,x0.w), pk2(x1.x,x1.y), pk2(x1.z,x1.w));
            *(uint4*)(&lA[row * 72 + cg * 16 + 8]) = make_uint4(pk2(x2.x,x2.y), pk2(x2.z,x2.w), pk2(x3.x,x3.y), pk2(x3.z,x3.w));
        }
        for (int c = wave; c < 18; c += 4) {
            const char* g = (const char*)Bimg + (size_t)kt * 18432 + c * 1024 + lane * 16;
            char* l = (char*)lB + c * 1024;
            __builtin_amdgcn_global_load_lds((const __attribute__((address_space(1))) u32*)g,
                                             (__attribute__((address_space(3))) u32*)l, 16, 0, 0);
        }
        __syncthreads();
        #pragma unroll
        for (int ks = 0; ks < 2; ++ks) {
            int kk = ks * 32 + (lane >> 4) * 8;
            s16x8 a[2], b[4];
            #pragma unroll
            for (int mt = 0; mt < 2; ++mt)
                a[mt] = *(const s16x8*)(&lA[(wm * 32 + mt * 16 + (lane & 15)) * 72 + kk]);
            #pragma unroll
            for (int nt = 0; nt < 4; ++nt)
                b[nt] = *(const s16x8*)(&lB[(wn * 64 + nt * 16 + (lane & 15)) * 72 + kk]);
            #pragma unroll
            for (int mt = 0; mt < 2; ++mt)
                #pragma unroll
                for (int nt = 0; nt < 4; ++nt)
                    acc[mt][nt] = __builtin_amdgcn_mfma_f32_16x16x32_bf16(a[mt], b[nt], acc[mt][nt], 0, 0, 0);
        }
        __syncthreads();
    }

    #pragma unroll
    for (int mt = 0; mt < 2; ++mt) {
        #pragma unroll
        for (int nt = 0; nt < 4; ++nt) {
            int colg = wn * 64 + nt * 16 + (lane & 15);
            float bb = bias[colg];
            #pragma unroll
            for (int i = 0; i < 4; ++i) {
                int rg = Mbase + wm * 32 + mt * 16 + (lane >> 4) * 4 + i;
                ((u16*)outp)[(size_t)rg * 128 + colg] = f2b(acc[mt][nt][i] + bb);
            }
        }
    }
}

// FUSED TAIL: out = W2 @ relu(W1 @ [relu(mask(Wo@ctx+bo)), src] + b1) + b2
__global__ __launch_bounds__(256) void gemm_tail(
    const u16* __restrict__ ctx, const float* __restrict__ src,
    const u16* __restrict__ woI, const u16* __restrict__ w1I, const u16* __restrict__ w2I,
    const float* __restrict__ bo, const float* __restrict__ b1, const float* __restrict__ b2,
    const unsigned char* __restrict__ flags, float* __restrict__ outp)
{
    __shared__ u16 lA[64 * 72];
    __shared__ u16 lB[128 * 72];
    __shared__ u16 s_a[64 * 136];
    const int tid = threadIdx.x;
    const int Mbase = blockIdx.x * 64;
    const int lane = tid & 63, wave = tid >> 6;
    const int wm = wave >> 1, wn = wave & 1;
    const int row = tid >> 2, cg = tid & 3;
    const size_t r = (size_t)(Mbase + row);

    #define STAGEB(IMG, KT) do {                                                            \
        for (int c_ = wave; c_ < 18; c_ += 4) {                                             \
            const char* g_ = (const char*)(IMG) + (size_t)(KT) * 18432 + c_ * 1024 + lane * 16; \
            char* l_ = (char*)lB + c_ * 1024;                                               \
            __builtin_amdgcn_global_load_lds((const __attribute__((address_space(1))) u32*)g_, \
                                             (__attribute__((address_space(3))) u32*)l_, 16, 0, 0); \
        }                                                                                   \
    } while (0)

    #define MFMA_STEP(ASRC, ASTRIDE, KOFF) do {                                             \
        _Pragma("unroll")                                                                   \
        for (int ks_ = 0; ks_ < 2; ++ks_) {                                                 \
            int kk_ = ks_ * 32 + (lane >> 4) * 8;                                           \
            s16x8 a_[2], b_[4];                                                             \
            _Pragma("unroll")                                                               \
            for (int mt_ = 0; mt_ < 2; ++mt_)                                               \
                a_[mt_] = *(const s16x8*)(&(ASRC)[(wm * 32 + mt_ * 16 + (lane & 15)) * (ASTRIDE) + (KOFF) + kk_]); \
            _Pragma("unroll")                                                               \
            for (int nt_ = 0; nt_ < 4; ++nt_)                                               \
                b_[nt_] = *(const s16x8*)(&lB[(wn * 64 + nt_ * 16 + (lane & 15)) * 72 + kk_]); \
            _Pragma("unroll")                                                               \
            for (int mt_ = 0; mt_ < 2; ++mt_)                                               \
                _Pragma("unroll")                                                           \
                for (int nt_ = 0; nt_ < 4; ++nt_)                                           \
                    acc[mt_][nt_] = __builtin_amdgcn_mfma_f32_16x16x32_bf16(a_[mt_], b_[nt_], acc[mt_][nt_], 0, 0, 0); \
        }                                                                                   \
    } while (0)

    f32x4 acc[2][4];

    // Phase 1: aout = relu(mask(Wo @ ctx + bo)) -> s_a
    #pragma unroll
    for (int mt = 0; mt < 2; ++mt)
        #pragma unroll
        for (int nt = 0; nt < 4; ++nt) acc[mt][nt] = (f32x4){0.f,0.f,0.f,0.f};

    for (int kt = 0; kt < 2; ++kt) {
        {
            const u16* ap = ctx + r * 128 + kt * 64 + cg * 16;
            *(uint4*)(&lA[row * 72 + cg * 16])     = *(const uint4*)ap;
            *(uint4*)(&lA[row * 72 + cg * 16 + 8]) = *(const uint4*)(ap + 8);
        }
        STAGEB(woI, kt);
        __syncthreads();
        MFMA_STEP(lA, 72, 0);
        __syncthreads();
    }
    #pragma unroll
    for (int mt = 0; mt < 2; ++mt) {
        #pragma unroll
        for (int nt = 0; nt < 4; ++nt) {
            int colg = wn * 64 + nt * 16 + (lane & 15);
            float bb = bo[colg];
            #pragma unroll
            for (int i = 0; i < 4; ++i) {
                int rl = wm * 32 + mt * 16 + (lane >> 4) * 4 + i;
                float val = acc[mt][nt][i] + bb;
                if (flags[Mbase + rl]) val = 0.f;
                s_a[rl * 136 + colg] = f2b(fmaxf(val, 0.f));
            }
        }
    }
    __syncthreads();

    // Phase 2: hmid = relu(W1 @ [aout(s_a), src] + b1) -> s_a
    #pragma unroll
    for (int mt = 0; mt < 2; ++mt)
        #pragma unroll
        for (int nt = 0; nt < 4; ++nt) acc[mt][nt] = (f32x4){0.f,0.f,0.f,0.f};

    for (int kt = 0; kt < 4; ++kt) {
        if (kt >= 2) {
            const float* ap = src + r * 128 + (kt - 2) * 64 + cg * 16;
            f32x4 x0 = *(const f32x4*)ap,       x1 = *(const f32x4*)(ap + 4);
            f32x4 x2 = *(const f32x4*)(ap + 8), x3 = *(const f32x4*)(ap + 12);
            *(uint4*)(&lA[row * 72 + cg * 16])     = make_uint4(pk2(x0.x,x0.y), pk2(x0.z,x0.w), pk2(x1.x,x1.y), pk2(x1.z,x1.w));
            *(uint4*)(&lA[row * 72 + cg * 16 + 8]) = make_uint4(pk2(x2.x,x2.y), pk2(x2.z,x2.w), pk2(x3.x,x3.y), pk2(x3.z,x3.w));
        }
        STAGEB(w1I, kt);
        __syncthreads();
        if (kt < 2) MFMA_STEP(s_a, 136, kt * 64);
        else        MFMA_STEP(lA, 72, 0);
        __syncthreads();
    }
    #pragma unroll
    for (int mt = 0; mt < 2; ++mt) {
        #pragma unroll
        for (int nt = 0; nt < 4; ++nt) {
            int colg = wn * 64 + nt * 16 + (lane & 15);
            float bb = b1[colg];
            #pragma unroll
            for (int i = 0; i < 4; ++i) {
                int rl = wm * 32 + mt * 16 + (lane >> 4) * 4 + i;
                s_a[rl * 136 + colg] = f2b(fmaxf(acc[mt][nt][i] + bb, 0.f));
            }
        }
    }
    __syncthreads();

    // Phase 3: out = W2 @ hmid + b2 -> global
    #pragma unroll
    for (int mt = 0; mt < 2; ++mt)
        #pragma unroll
        for (int nt = 0; nt < 4; ++nt) acc[mt][nt] = (f32x4){0.f,0.f,0.f,0.f};

    for (int kt = 0; kt < 2; ++kt) {
        STAGEB(w2I, kt);
        __syncthreads();
        MFMA_STEP(s_a, 136, kt * 64);
        __syncthreads();
    }
    #pragma unroll
    for (int mt = 0; mt < 2; ++mt) {
        #pragma unroll
        for (int nt = 0; nt < 4; ++nt) {
            int colg = wn * 64 + nt * 16 + (lane & 15);
            float bb = b2[colg];
            #pragma unroll
            for (int i = 0; i < 4; ++i) {
                int rg = Mbase + wm * 32 + mt * 16 + (lane >> 4) * 4 + i;
                outp[(size_t)rg * 128 + colg] = acc[mt][nt][i] + bb;
            }
        }
    }
    #undef STAGEB
    #undef MFMA_STEP
}

// ==================== tier-2: round-2 path (known-good) ====================

__global__ void prep_pack_r2(const float* __restrict__ wkt, const float* __restrict__ wvt,
                             const float* __restrict__ Wq, const float* __restrict__ Wo,
                             const float* __restrict__ W1, const float* __restrict__ W2,
                             u16* __restrict__ bpack, u32* __restrict__ wq2, u32* __restrict__ wo2,
                             u32* __restrict__ w12, u32* __restrict__ w22)
{
    const int id = blockIdx.x * 256 + threadIdx.x;
    if (id < 98304) {
        int kt = id >> 14;
        int o  = id & 16383;
        int n  = o >> 6;
        int kk = (o & 63) ^ ((n & 7) << 3);
        int k  = kt * 64 + kk;
        float v = 0.f;
        if (k < KD) v = (n < FF) ? wkt[k * FF + n] : wvt[k * FF + (n - FF)];
        bpack[id] = f2b(v);
    } else if (id < 106496) {
        int e = id - 98304; int j = e >> 6, tt = e & 63;
        wq2[e] = (u32)f2b(Wq[tt * FF + j]) | ((u32)f2b(Wq[(tt + 64) * FF + j]) << 16);
    } else if (id < 114688) {
        int e = id - 106496; int j = e >> 6, tt = e & 63;
        wo2[e] = (u32)f2b(Wo[tt * FF + j]) | ((u32)f2b(Wo[(tt + 64) * FF + j]) << 16);
    } else if (id < 131072) {
        int e = id - 114688; int j = e >> 6, tt = e & 63;
        w12[e] = (u32)f2b(W1[tt * 2 * FF + j]) | ((u32)f2b(W1[(tt + 64) * 2 * FF + j]) << 16);
    } else if (id < 139264) {
        int e = id - 131072; int j = e >> 6, tt = e & 63;
        w22[e] = (u32)f2b(W2[tt * FF + j]) | ((u32)f2b(W2[(tt + 64) * FF + j]) << 16);
    }
}

__global__ __launch_bounds__(512) void kv_gemm_r2(
    const float* __restrict__ nbr, const float* __restrict__ edg, const float* __restrict__ tmf,
    const float* __restrict__ wgt, const float* __restrict__ bk, const float* __restrict__ bv,
    const u16* __restrict__ bpack, const float* __restrict__ kfb, const float* __restrict__ vfb,
    u16* __restrict__ kvout)
{
    __shared__ u16 lA[128 * 64];
    __shared__ u16 lB[256 * 64];
    const int tid = threadIdx.x;
    const int Mbase = blockIdx.x * 128;
    const int lane = tid & 63, wave = tid >> 6;
    const int wm = wave >> 2, wn = wave & 3;

    f32x4 acc[4][4] = {};
    const int rq = tid >> 4;
    const int cq = tid & 15;

    for (int kt = 0; kt < 6; ++kt) {
        #pragma unroll
        for (int i = 0; i < 4; ++i) {
            int row = rq + i * 32;
            size_t r = (size_t)(Mbase + row);
            f32x4 v;
            if (kt < 2)       v = *(const f32x4*)(nbr + r * 128 + kt * 64 + cq * 4);
            else if (kt < 4)  v = *(const f32x4*)(edg + r * 128 + (kt - 2) * 64 + cq * 4);
            else if (kt == 4) v = *(const f32x4*)(tmf + r * 100 + cq * 4);
            else if (cq < 9)  v = *(const f32x4*)(tmf + r * 100 + 64 + cq * 4);
            else              v = (f32x4){0.f, 0.f, 0.f, 0.f};
            int off = row * 64 + ((cq * 4) ^ ((row & 7) << 3));
            *(uint2*)(&lA[off]) = make_uint2(pk2(v.x, v.y), pk2(v.z, v.w));
        }
        #pragma unroll
        for (int i = 0; i < 4; ++i) {
            int boff = wave * 4096 + i * 1024;
            const char* g = (const char*)bpack + (size_t)kt * 32768 + boff + lane * 16;
            char* l = (char*)lB + boff;
            __builtin_amdgcn_global_load_lds((const __attribute__((address_space(1))) u32*)g,
                                             (__attribute__((address_space(3))) u32*)l, 16, 0, 0);
        }
        __syncthreads();
        #pragma unroll
        for (int ks = 0; ks < 2; ++ks) {
            int kk = ks * 32 + (lane >> 4) * 8;
            s16x8 a[4], b[4];
            #pragma unroll
            for (int mt = 0; mt < 4; ++mt) {
                int m = wm * 64 + mt * 16 + (lane & 15);
                a[mt] = *(const s16x8*)(&lA[m * 64 + (kk ^ ((m & 7) << 3))]);
            }
            #pragma unroll
            for (int nt = 0; nt < 4; ++nt) {
                int n = wn * 64 + nt * 16 + (lane & 15);
                b[nt] = *(const s16x8*)(&lB[n * 64 + (kk ^ ((n & 7) << 3))]);
            }
            #pragma unroll
            for (int mt = 0; mt < 4; ++mt)
                #pragma unroll
                for (int nt = 0; nt < 4; ++nt)
                    acc[mt][nt] = __builtin_amdgcn_mfma_f32_16x16x32_bf16(a[mt], b[nt], acc[mt][nt], 0, 0, 0);
        }
        __syncthreads();
    }

    #pragma unroll
    for (int mt = 0; mt < 4; ++mt) {
        float w4[4];
        #pragma unroll
        for (int i = 0; i < 4; ++i)
            w4[i] = wgt[Mbase + wm * 64 + mt * 16 + (lane >> 4) * 4 + i];
        #pragma unroll
        for (int nt = 0; nt < 4; ++nt) {
            int c = wn * 64 + nt * 16 + (lane & 15);
            float fb   = (c < FF) ? kfb[c] : vfb[c - FF];
            float bias = (c < FF) ? bk[c]  : bv[c - FF];
            #pragma unroll
            for (int i = 0; i < 4; ++i) {
                int rr = Mbase + wm * 64 + mt * 16 + (lane >> 4) * 4 + i;
                float val = fmaf(acc[mt][nt][i] + fb, w4[i], bias);
                kvout[(size_t)rr * 256 + c] = f2b(val);
            }
        }
    }
}

__global__ __launch_bounds__(64) void gat_attn_r2(
    const float* __restrict__ src, const void* __restrict__ maskp,
    const float* __restrict__ bq, const float* __restrict__ bo,
    const float* __restrict__ b1, const float* __restrict__ b2,
    const u16* __restrict__ kv, const u32* __restrict__ wq2, const u32* __restrict__ wo2,
    const u32* __restrict__ w12, const u32* __restrict__ w22,
    const int* __restrict__ flagp, float* __restrict__ out)
{
    const int b = blockIdx.x, t = threadIdx.x;
    __shared__ u16 kls[NN * 132];
    __shared__ float s_src[FF], s_q[FF], s_ctx[FF], s_out[FF], s_h[FF];
    __shared__ float s_sc[2 * NN];

    const int flag = *flagp;
    bool mybit = false;
    if (t < NN) {
        if (flag) mybit = ((const unsigned char*)maskp)[b * NN + t] != 0;
        else      mybit = ((const int*)maskp)[b * NN + t] != 0;
    }
    u64 bal = __ballot(mybit);
    u32 mb = (u32)(bal & 0xFFFFFull);
    const bool invalid = (mb == 0xFFFFFu);
    if (invalid) mb &= ~1u;

    s_src[t] = src[(size_t)b * FF + t];
    s_src[t + 64] = src[(size_t)b * FF + 64 + t];

    float v0[NN], v1[NN];
    #pragma unroll
    for (int n = 0; n < NN; ++n) {
        const u16* row = kv + ((size_t)b * NN + n) * 256;
        kls[n * 132 + t]      = row[t];
        kls[n * 132 + 64 + t] = row[64 + t];
        v0[n] = b2f(row[128 + t]);
        v1[n] = b2f(row[192 + t]);
    }
    __syncthreads();

    {
        float q0 = bq[t], q1 = bq[64 + t];
        for (int j = 0; j < FF; ++j) {
            u32 u = wq2[j * 64 + t];
            float sj = s_src[j];
            q0 = fmaf(blo(u), sj, q0);
            q1 = fmaf(bhi(u), sj, q1);
        }
        s_q[t] = q0; s_q[64 + t] = q1;
    }
    __syncthreads();

    if (t < 2 * NN) {
        int h = t / NN, n = t - (t / NN) * NN;
        const u16* kr = kls + n * 132 + h * 64;
        const float* qr = s_q + h * 64;
        float s = 0.f;
        #pragma unroll
        for (int d = 0; d < 64; ++d) s = fmaf(qr[d], b2f(kr[d]), s);
        s *= 0.125f;
        s_sc[t] = ((mb >> n) & 1u) ? -INFINITY : s;
    }
    __syncthreads();
    if (t < 2) {
        float mx = -INFINITY;
        for (int n = 0; n < NN; ++n) mx = fmaxf(mx, s_sc[t * NN + n]);
        float e[NN]; float sum = 0.f;
        for (int n = 0; n < NN; ++n) { e[n] = expf(s_sc[t * NN + n] - mx); sum += e[n]; }
        float inv = 1.f / sum;
        for (int n = 0; n < NN; ++n) s_sc[t * NN + n] = e[n] * inv;
    }
    __syncthreads();

    {
        float c0 = 0.f, c1 = 0.f;
        #pragma unroll
        for (int n = 0; n < NN; ++n) {
            c0 = fmaf(s_sc[n],      v0[n], c0);
            c1 = fmaf(s_sc[NN + n], v1[n], c1);
        }
        s_ctx[t] = c0; s_ctx[64 + t] = c1;
    }
    __syncthreads();

    {
        float o0 = bo[t], o1 = bo[64 + t];
        for (int j = 0; j < FF; ++j) {
            u32 u = wo2[j * 64 + t];
            float cj = s_ctx[j];
            o0 = fmaf(blo(u), cj, o0);
            o1 = fmaf(bhi(u), cj, o1);
        }
        if (invalid) { o0 = 0.f; o1 = 0.f; }
        o0 = fmaxf(o0, 0.f); o1 = fmaxf(o1, 0.f);
        s_out[t] = o0; s_out[64 + t] = o1;
    }
    __syncthreads();

    {
        float h0 = b1[t], h1 = b1[64 + t];
        for (int j = 0; j < FF; ++j) {
            u32 u = w12[j * 64 + t];
            float xj = s_out[j];
            h0 = fmaf(blo(u), xj, h0);
            h1 = fmaf(bhi(u), xj, h1);
        }
        for (int j = 0; j < FF; ++j) {
            u32 u = w12[(FF + j) * 64 + t];
            float xj = s_src[j];
            h0 = fmaf(blo(u), xj, h0);
            h1 = fmaf(bhi(u), xj, h1);
        }
        h0 = fmaxf(h0, 0.f); h1 = fmaxf(h1, 0.f);
        s_h[t] = h0; s_h[64 + t] = h1;
    }
    __syncthreads();

    {
        float f0 = b2[t], f1 = b2[64 + t];
        for (int j = 0; j < FF; ++j) {
            u32 u = w22[j * 64 + t];
            float hj = s_h[j];
            f0 = fmaf(blo(u), hj, f0);
            f1 = fmaf(bhi(u), hj, f1);
        }
        out[(size_t)b * FF + t] = f0;
        out[(size_t)b * FF + 64 + t] = f1;
    }
}

// ==================== tier-3 fallback (round-1, known-good) ====================

#define FB_WKT  0
#define FB_WVT  (FB_WKT + KD*FF)
#define FB_KB   (FB_WVT + KD*FF)
#define FB_VB   (FB_KB + FF)
#define FB_WQT  (FB_VB + FF)
#define FB_WOT  (FB_WQT + FF*FF)
#define FB_W1T  (FB_WOT + FF*FF)
#define FB_W2T  (FB_W1T + 2*FF*FF)
#define FB_FLAG (FB_W2T + FF*FF)

__global__ void gat_prep_fb(const float* __restrict__ Wt, const float* __restrict__ bt,
                            const float* __restrict__ Wq, const float* __restrict__ Wk,
                            const float* __restrict__ Wv, const float* __restrict__ Wo,
                            const float* __restrict__ W1, const float* __restrict__ W2,
                            const u32* __restrict__ maskw, float* __restrict__ ws)
{
    const int blk = blockIdx.x;
    const int t = threadIdx.x;
    if (blk < KD) {
        __shared__ float col[FF];
        col[t] = Wt[t * KD + blk];
        __syncthreads();
        float ak = 0.f, av = 0.f;
        for (int j = 0; j < FF; ++j) {
            float c = col[j];
            ak = fmaf(Wk[t * FF + j], c, ak);
            av = fmaf(Wv[t * FF + j], c, av);
        }
        ws[FB_WKT + blk * FF + t] = ak;
        ws[FB_WVT + blk * FF + t] = av;
    } else if (blk == KD) {
        float ak = 0.f, av = 0.f;
        for (int j = 0; j < FF; ++j) {
            float c = bt[j];
            ak = fmaf(Wk[t * FF + j], c, ak);
            av = fmaf(Wv[t * FF + j], c, av);
        }
        ws[FB_KB + t] = ak;
        ws[FB_VB + t] = av;
    } else if (blk == KD + 1) {
        int any = 0;
        for (int i = t; i < 8192; i += 128) any |= (maskw[i] > 1u) ? 1 : 0;
        any = __any(any) ? 1 : 0;
        __shared__ int red[2];
        if ((t & 63) == 0) red[t >> 6] = any;
        __syncthreads();
        if (t == 0) ((int*)ws)[FB_FLAG] = (red[0] | red[1]) ? 1 : 0;
    } else {
        int id = (blk - (KD + 2)) * 128 + t;
        if (id < FF * FF) {
            int k = id >> 7, f = id & 127;
            ws[FB_WQT + id] = Wq[f * FF + k];
        } else if (id < 2 * FF * FF) {
            int e = id - FF * FF; int k = e >> 7, f = e & 127;
            ws[FB_WOT + e] = Wo[f * FF + k];
        } else if (id < 4 * FF * FF) {
            int e = id - 2 * FF * FF; int j = e >> 7, f = e & 127;
            ws[FB_W1T + e] = W1[f * (2 * FF) + j];
        } else if (id < 5 * FF * FF) {
            int e = id - 4 * FF * FF; int k = e >> 7, f = e & 127;
            ws[FB_W2T + e] = W2[f * FF + k];
        }
    }
}

__global__ __launch_bounds__(64) void gat_main_fb(
    const float* __restrict__ src, const float* __restrict__ nbr,
    const float* __restrict__ tmf, const float* __restrict__ edg,
    const void* __restrict__ maskp, const float* __restrict__ wgt,
    const float* __restrict__ bq, const float* __restrict__ bk,
    const float* __restrict__ bv, const float* __restrict__ bo,
    const float* __restrict__ b1, const float* __restrict__ b2,
    const float* __restrict__ ws, float* __restrict__ out)
{
    const int b = blockIdx.x;
    const int t = threadIdx.x;
    __shared__ __align__(16) float kin[KD * NN];
    __shared__ float s_src[FF], s_q[FF], s_ctx[FF], s_out[FF], s_h[FF];
    __shared__ float s_w[NN], s_sc[2 * NN];

    const int flag = ((const int*)ws)[FB_FLAG];
    bool mybit = false;
    if (t < NN) {
        if (flag) mybit = ((const unsigned char*)maskp)[b * NN + t] != 0;
        else      mybit = ((const int*)maskp)[b * NN + t] != 0;
    }
    u64 bal = __ballot(mybit);
    u32 mb = (u32)(bal & 0xFFFFFull);
    const bool invalid = (mb == 0xFFFFFu);
    if (invalid) mb &= ~1u;

    s_src[t] = src[(size_t)b * FF + t];
    s_src[t + 64] = src[(size_t)b * FF + 64 + t];
    if (t < NN) s_w[t] = wgt[(size_t)b * NN + t];

    for (int idx = t; idx < NN * FF; idx += 64) {
        int n = idx >> 7, j = idx & 127;
        kin[j * NN + n]         = nbr[((size_t)b * NN + n) * FF + j];
        kin[(128 + j) * NN + n] = edg[((size_t)b * NN + n) * EE + j];
    }
    for (int idx = t; idx < NN * TT; idx += 64) {
        int n = idx / TT, j = idx - n * TT;
        kin[(256 + j) * NN + n] = tmf[((size_t)b * NN + n) * TT + j];
    }
    __syncthreads();

    const float* wkt = ws + FB_WKT;
    const float* wvt = ws + FB_WVT;
    float ak0[NN], ak1[NN], av0[NN], av1[NN];
#pragma unroll
    for (int n = 0; n < NN; ++n) { ak0[n] = 0.f; ak1[n] = 0.f; av0[n] = 0.f; av1[n] = 0.f; }
    for (int k = 0; k < KD; ++k) {
        float wk0 = wkt[k * FF + t],      wk1 = wkt[k * FF + 64 + t];
        float wv0 = wvt[k * FF + t],      wv1 = wvt[k * FF + 64 + t];
        const float4* cp = (const float4*)(kin + k * NN);
        float4 ca = cp[0], cb = cp[1], cc = cp[2], cd = cp[3], ce = cp[4];
        const float c[NN] = { ca.x, ca.y, ca.z, ca.w,  cb.x, cb.y, cb.z, cb.w,
                              cc.x, cc.y, cc.z, cc.w,  cd.x, cd.y, cd.z, cd.w,
                              ce.x, ce.y, ce.z, ce.w };
#pragma unroll
        for (int n = 0; n < NN; ++n) {
            ak0[n] = fmaf(wk0, c[n], ak0[n]);
            ak1[n] = fmaf(wk1, c[n], ak1[n]);
            av0[n] = fmaf(wv0, c[n], av0[n]);
            av1[n] = fmaf(wv1, c[n], av1[n]);
        }
    }
    __syncthreads();

    float* kls = kin;
    float* vls = kin + NN * 129;
    {
        const float kb0 = ws[FB_KB + t], kb1 = ws[FB_KB + 64 + t];
        const float vb0 = ws[FB_VB + t], vb1 = ws[FB_VB + 64 + t];
        const float k0b = bk[t], k1b = bk[64 + t];
        const float v0b = bv[t], v1b = bv[64 + t];
#pragma unroll
        for (int n = 0; n < NN; ++n) {
            float wn = s_w[n];
            kls[n * 129 + t]      = fmaf(wn, ak0[n] + kb0, k0b);
            kls[n * 129 + 64 + t] = fmaf(wn, ak1[n] + kb1, k1b);
            vls[n * 129 + t]      = fmaf(wn, av0[n] + vb0, v0b);
            vls[n * 129 + 64 + t] = fmaf(wn, av1[n] + vb1, v1b);
        }
    }
    {
        const float* wqT = ws + FB_WQT;
        float q0 = bq[t], q1 = bq[64 + t];
        for (int j = 0; j < FF; ++j) {
            float sj = s_src[j];
            q0 = fmaf(wqT[j * FF + t], sj, q0);
            q1 = fmaf(wqT[j * FF + 64 + t], sj, q1);
        }
        s_q[t] = q0; s_q[64 + t] = q1;
    }
    __syncthreads();

    if (t < 2 * NN) {
        int h = t / NN, n = t - (t / NN) * NN;
        const float* kr = kls + n * 129 + h * 64;
        const float* qr = s_q + h * 64;
        float s = 0.f;
#pragma unroll
        for (int d = 0; d < 64; ++d) s = fmaf(qr[d], kr[d], s);
        s *= 0.125f;
        s_sc[t] = ((mb >> n) & 1u) ? -INFINITY : s;
    }
    __syncthreads();
    if (t < 2) {
        float mx = -INFINITY;
        for (int n = 0; n < NN; ++n) mx = fmaxf(mx, s_sc[t * NN + n]);
        float e[NN]; float sum = 0.f;
        for (int n = 0; n < NN; ++n) { e[n] = expf(s_sc[t * NN + n] - mx); sum += e[n]; }
        float inv = 1.f / sum;
        for (int n = 0; n < NN; ++n) s_sc[t * NN + n] = e[n] * inv;
    }
    __syncthreads();

    {
        float c0 = 0.f, c1 = 0.f;
#pragma unroll
        for (int n = 0; n < NN; ++n) {
            c0 = fmaf(s_sc[n],      vls[n * 129 + t],      c0);
            c1 = fmaf(s_sc[NN + n], vls[n * 129 + 64 + t], c1);
        }
        s_ctx[t] = c0; s_ctx[64 + t] = c1;
    }
    __syncthreads();

    {
        const float* woT = ws + FB_WOT;
        float o0 = bo[t], o1 = bo[64 + t];
        for (int j = 0; j < FF; ++j) {
            float cj = s_ctx[j];
            o0 = fmaf(woT[j * FF + t], cj, o0);
            o1 = fmaf(woT[j * FF + 64 + t], cj, o1);
        }
        if (invalid) { o0 = 0.f; o1 = 0.f; }
        o0 = fmaxf(o0, 0.f); o1 = fmaxf(o1, 0.f);
        s_out[t] = o0; s_out[64 + t] = o1;
    }
    __syncthreads();

    {
        const float* w1T = ws + FB_W1T;
        float h0 = b1[t], h1 = b1[64 + t];
        for (int j = 0; j < FF; ++j) {
            float xj = s_out[j];
            h0 = fmaf(w1T[j * FF + t], xj, h0);
            h1 = fmaf(w1T[j * FF + 64 + t], xj, h1);
        }
        for (int j = 0; j < FF; ++j) {
            float xj = s_src[j];
            h0 = fmaf(w1T[(FF + j) * FF + t], xj, h0);
            h1 = fmaf(w1T[(FF + j) * FF + 64 + t], xj, h1);
        }
        h0 = fmaxf(h0, 0.f); h1 = fmaxf(h1, 0.f);
        s_h[t] = h0; s_h[64 + t] = h1;
    }
    __syncthreads();

    {
        const float* w2T = ws + FB_W2T;
        float f0 = b2[t], f1 = b2[64 + t];
        for (int j = 0; j < FF; ++j) {
            float hj = s_h[j];
            f0 = fmaf(w2T[j * FF + t], hj, f0);
            f1 = fmaf(w2T[j * FF + 64 + t], hj, f1);
        }
        out[(size_t)b * FF + t] = f0;
        out[(size_t)b * FF + 64 + t] = f1;
    }
}

// ==================== host ====================

extern "C" void kernel_launch(void* const* d_in, const int* in_sizes, int n_in,
                              void* d_out, int out_size, void* d_ws, size_t ws_size,
                              hipStream_t stream)
{
    const float* src = (const float*)d_in[0];
    const float* nbr = (const float*)d_in[1];
    const float* tmf = (const float*)d_in[2];
    const float* edg = (const float*)d_in[3];
    const void*  msk = d_in[4];
    const float* wgt = (const float*)d_in[5];
    const float* Wt  = (const float*)d_in[6];
    const float* bt  = (const float*)d_in[7];
    const float* Wq  = (const float*)d_in[8];
    const float* bq  = (const float*)d_in[9];
    const float* Wk  = (const float*)d_in[10];
    const float* bk  = (const float*)d_in[11];
    const float* Wv  = (const float*)d_in[12];
    const float* bv  = (const float*)d_in[13];
    const float* Wo  = (const float*)d_in[14];
    const float* bo  = (const float*)d_in[15];
    const float* W1  = (const float*)d_in[16];
    const float* b1  = (const float*)d_in[17];
    const float* W2  = (const float*)d_in[18];
    const float* b2  = (const float*)d_in[19];

    const int B = in_sizes[0] / FF;
    const size_t M = (size_t)B * NN;
    constexpr int NG = 8;

    // tier-1 layout (bytes)
    size_t o1 = 0;
    size_t t1_qa   = o1; o1 += (size_t)B * 256;   // Q bf16
    size_t t1_ch   = o1; o1 += (size_t)B * 256;   // ctx bf16
    size_t t1_kvB  = o1; o1 += 393216;            // frag-major B image
    size_t t1_wqI  = o1; o1 += 36864;
    size_t t1_woI  = o1; o1 += 36864;
    size_t t1_w1I  = o1; o1 += 73728;
    size_t t1_w2I  = o1; o1 += 36864;
    size_t t1_wkt  = o1; o1 += (size_t)KD * FF * 4;
    size_t t1_wvt  = o1; o1 += (size_t)KD * FF * 4;
    size_t t1_kfb  = o1; o1 += 512;
    size_t t1_vfb  = o1; o1 += 512;
    size_t t1_flg  = o1; o1 += (size_t)B;         // invalid flags
    o1 = (o1 + 255) & ~(size_t)255;
    size_t t1_flag = o1; o1 += 64;
    const size_t need1 = o1;

    // tier-2 layout (bytes)
    size_t o2 = 0;
    size_t t2_kv    = o2; o2 += M * 512;
    size_t t2_bpack = o2; o2 += 98304ull * 2;
    size_t t2_wkt   = o2; o2 += (size_t)KD * FF * 4;
    size_t t2_wvt   = o2; o2 += (size_t)KD * FF * 4;
    size_t t2_kfb   = o2; o2 += 512;
    size_t t2_vfb   = o2; o2 += 512;
    size_t t2_wq2   = o2; o2 += 32768;
    size_t t2_wo2   = o2; o2 += 32768;
    size_t t2_w12   = o2; o2 += 65536;
    size_t t2_w22   = o2; o2 += 32768;
    size_t t2_flag  = o2; o2 += 64;
    const size_t need2 = o2;

    char* w = (char*)d_ws;

    if (ws_size >= need1 && (B % (4 * NG * 2)) == 0) {   // B % 64 == 0 and B % 32 == 0
        u16*   qa    = (u16*)(w + t1_qa);
        u16*   ch    = (u16*)(w + t1_ch);
        u16*   kvB   = (u16*)(w + t1_kvB);
        u16*   wqI   = (u16*)(w + t1_wqI);
        u16*   woI   = (u16*)(w + t1_woI);
        u16*   w1I   = (u16*)(w + t1_w1I);
        u16*   w2I   = (u16*)(w + t1_w2I);
        float* wktp  = (float*)(w + t1_wkt);
        float* wvtp  = (float*)(w + t1_wvt);
        float* kfb   = (float*)(w + t1_kfb);
        float* vfb   = (float*)(w + t1_vfb);
        unsigned char* flg = (unsigned char*)(w + t1_flg);
        int*   flagp = (int*)(w + t1_flag);

        prep_fuse<<<dim3(KD + 2), dim3(128), 0, stream>>>(Wt, bt, Wk, Wv,
            (const u32*)msk, wktp, wvtp, kfb, vfb, flagp);
        prep_pack_v4<<<dim3(1128), dim3(256), 0, stream>>>(wktp, wvtp, Wq, Wo, W1, W2,
            kvB, wqI, woI, w1I, w2I);
        gemm_small<GM_Q><<<dim3(B / 64), dim3(256), 0, stream>>>(
            (const void*)src, nullptr, wqI, bq, nullptr, (void*)qa);
        kv_attn_fused8<NG><<<dim3(B / (4 * NG)), dim3(512), 0, stream>>>(
            nbr, edg, tmf, wgt, bk, bv, kvB, kfb, vfb, qa, msk, flagp, ch, flg);
        gemm_tail<<<dim3(B / 64), dim3(256), 0, stream>>>(
            ch, src, woI, w1I, w2I, bo, b1, b2, flg, (float*)d_out);
    } else if (ws_size >= need2 && (M % 128) == 0) {
        u16*   kvp   = (u16*)(w + t2_kv);
        u16*   bpack = (u16*)(w + t2_bpack);
        float* wktp  = (float*)(w + t2_wkt);
        float* wvtp  = (float*)(w + t2_wvt);
        float* kfb   = (float*)(w + t2_kfb);
        float* vfb   = (float*)(w + t2_vfb);
        u32*   wq2   = (u32*)(w + t2_wq2);
        u32*   wo2   = (u32*)(w + t2_wo2);
        u32*   w12   = (u32*)(w + t2_w12);
        u32*   w22   = (u32*)(w + t2_w22);
        int*   flagp = (int*)(w + t2_flag);

        prep_fuse<<<dim3(KD + 2), dim3(128), 0, stream>>>(Wt, bt, Wk, Wv,
            (const u32*)msk, wktp, wvtp, kfb, vfb, flagp);
        prep_pack_r2<<<dim3(544), dim3(256), 0, stream>>>(wktp, wvtp, Wq, Wo, W1, W2,
            bpack, wq2, wo2, w12, w22);
        kv_gemm_r2<<<dim3((int)(M / 128)), dim3(512), 0, stream>>>(
            nbr, edg, tmf, wgt, bk, bv, bpack, kfb, vfb, kvp);
        gat_attn_r2<<<dim3(B), dim3(64), 0, stream>>>(
            src, msk, bq, bo, b1, b2, kvp, wq2, wo2, w12, w22, flagp, (float*)d_out);
    } else {
        float* ws = (float*)d_ws;
        gat_prep_fb<<<dim3(KD + 2 + 640), dim3(128), 0, stream>>>(
            Wt, bt, Wq, Wk, Wv, Wo, W1, W2, (const u32*)msk, ws);
        gat_main_fb<<<dim3(B), dim3(64), 0, stream>>>(
            src, nbr, tmf, edg, msk, wgt, bq, bk, bv, bo, b1, b2, ws, (float*)d_out);
    }
}

// Round 13
// 204.004 us; speedup vs baseline: 1.2269x; 1.2269x over previous
//
#include <hip/hip_runtime.h>
#include <math.h>

#define NN 20
#define FF 128
#define TT 100
#define EE 128
#define KD 356

typedef unsigned int u32;
typedef unsigned short u16;
typedef unsigned long long u64;
typedef __attribute__((ext_vector_type(4))) float f32x4;
typedef __attribute__((ext_vector_type(8))) short s16x8;
typedef __attribute__((ext_vector_type(4))) u32 u32x4;

__device__ __forceinline__ u16 f2b(float f) {
    u32 u = __float_as_uint(f);
    u32 r = u + 0x7FFFu + ((u >> 16) & 1u);   // RNE
    return (u16)(r >> 16);
}
__device__ __forceinline__ float b2f(u16 h) { return __uint_as_float(((u32)h) << 16); }
__device__ __forceinline__ float blo(u32 u){ return __uint_as_float(u << 16); }
__device__ __forceinline__ float bhi(u32 u){ return __uint_as_float(u & 0xFFFF0000u); }
__device__ __forceinline__ u32 pk2(float a, float b){ return (u32)f2b(a) | ((u32)f2b(b) << 16); }
__device__ __forceinline__ u32 cvtpk(float a, float b){
    u32 d; asm("v_cvt_pk_bf16_f32 %0, %1, %2" : "=v"(d) : "v"(a), "v"(b)); return d;
}

// ==================== tier-1 fast path ====================

__global__ void prep_fuse(const float* __restrict__ Wt, const float* __restrict__ bt,
                          const float* __restrict__ Wk, const float* __restrict__ Wv,
                          const u32* __restrict__ maskw,
                          float* __restrict__ wkt, float* __restrict__ wvt,
                          float* __restrict__ kfb, float* __restrict__ vfb, int* __restrict__ flagp)
{
    const int blk = blockIdx.x, t = threadIdx.x;  // 128 threads
    if (blk < KD) {
        __shared__ float col[FF];
        col[t] = Wt[t * KD + blk];
        __syncthreads();
        float ak = 0.f, av = 0.f;
        for (int j = 0; j < FF; ++j) {
            float c = col[j];
            ak = fmaf(Wk[t * FF + j], c, ak);
            av = fmaf(Wv[t * FF + j], c, av);
        }
        wkt[blk * FF + t] = ak;
        wvt[blk * FF + t] = av;
    } else if (blk == KD) {
        float ak = 0.f, av = 0.f;
        for (int j = 0; j < FF; ++j) {
            float c = bt[j];
            ak = fmaf(Wk[t * FF + j], c, ak);
            av = fmaf(Wv[t * FF + j], c, av);
        }
        kfb[t] = ak; vfb[t] = av;
    } else {
        int any = 0;
        for (int i = t; i < 8192; i += 128) any |= (maskw[i] > 1u) ? 1 : 0;
        any = __any(any) ? 1 : 0;
        __shared__ int red[2];
        if ((t & 63) == 0) red[t >> 6] = any;
        __syncthreads();
        if (t == 0) *flagp = (red[0] | red[1]) ? 1 : 0;
    }
}

// prep2 v4: fragment-major B image + padded LDS images for small GEMMs.
__global__ void prep_pack_v4(const float* __restrict__ wkt, const float* __restrict__ wvt,
                             const float* __restrict__ Wq, const float* __restrict__ Wo,
                             const float* __restrict__ W1, const float* __restrict__ W2,
                             u16* __restrict__ kvB, u16* __restrict__ wqI, u16* __restrict__ woI,
                             u16* __restrict__ w1I, u16* __restrict__ w2I)
{
    const int id = blockIdx.x * 256 + threadIdx.x;   // 1128*256 = 288768
    if (id < 196608) {
        int chunk = id >> 9, e = id & 511;
        int ln = e >> 3, ee = e & 7;
        int kt = chunk >> 4, nb = chunk & 15;
        int k = kt * 32 + (ln >> 4) * 8 + ee;
        int n = nb * 16 + (ln & 15);
        float v = 0.f;
        if (k < KD) v = (n < FF) ? wkt[k * FF + n] : wvt[k * FF + (n - FF)];
        kvB[id] = f2b(v);
    } else if (id < 215040) {
        int e = id - 196608; int rem = e % 9216;
        int n = rem / 72, kk = rem % 72; int k = (e / 9216) * 64 + kk;
        wqI[e] = f2b(kk < 64 ? Wq[n * FF + k] : 0.f);
    } else if (id < 233472) {
        int e = id - 215040; int rem = e % 9216;
        int n = rem / 72, kk = rem % 72; int k = (e / 9216) * 64 + kk;
        woI[e] = f2b(kk < 64 ? Wo[n * FF + k] : 0.f);
    } else if (id < 270336) {
        int e = id - 233472; int rem = e % 9216;
        int n = rem / 72, kk = rem % 72; int k = (e / 9216) * 64 + kk;
        w1I[e] = f2b(kk < 64 ? W1[n * 2 * FF + k] : 0.f);
    } else if (id < 288768) {
        int e = id - 270336; int rem = e % 9216;
        int n = rem / 72, kk = rem % 72; int k = (e / 9216) * 64 + kk;
        w2I[e] = f2b(kk < 64 ? W2[n * FF + k] : 0.f);
    }
}

// FUSED v7 (best measured: 192 us).
__global__ __launch_bounds__(512) void kv_attn_fused7(
    const float* __restrict__ nbr, const float* __restrict__ edg, const float* __restrict__ tmf,
    const float* __restrict__ wgt, const float* __restrict__ bk, const float* __restrict__ bv,
    const u16* __restrict__ kvB, const float* __restrict__ kfb, const float* __restrict__ vfb,
    const u16* __restrict__ Qg, const void* __restrict__ maskp, const int* __restrict__ flagp,
    u16* __restrict__ ctxout, unsigned char* __restrict__ flags)
{
    __shared__ __align__(16) u16 smem[15680];   // 31360B = A ring 3x10240 + p_lds 640
    char* sb = (char*)smem;
    float* p_lds = (float*)(sb + 30720);
    u16* kls = (u16*)sb;                         // aliased after GEMM (21120B)

    const int tid = threadIdx.x;
    const int lane = tid & 63, wave = tid >> 6;  // 8 waves
    const int wn = wave;
    const int Mbase = blockIdx.x * 80;
    const int Bbase = blockIdx.x * 4;
    const int kg = lane >> 4, l16 = lane & 15;

    f32x4 acc[5][2] = {};
    s16x8 br[2][2];
    f32x4 tl[5];

    #define STAGE_CHUNK(C, KT) do {                                                         \
        int row_ = (C) * 8 + (lane >> 3);                                                   \
        int x_ = (lane & 7) ^ (row_ & 7);                                                   \
        const float* g_;                                                                    \
        if ((KT) < 4)      g_ = nbr + (size_t)(Mbase + row_) * 128 + (KT) * 32 + x_ * 4;    \
        else if ((KT) < 8) g_ = edg + (size_t)(Mbase + row_) * 128 + ((KT)-4) * 32 + x_ * 4;\
        else               g_ = tmf + (size_t)(Mbase + row_) * 100 + ((KT)-8) * 32 + x_ * 4;\
        __builtin_amdgcn_global_load_lds((const __attribute__((address_space(1))) u32*)g_,  \
            (__attribute__((address_space(3))) u32*)(sb + ((KT)%3)*10240 + (C)*1024), 16, 0, 0); \
    } while (0)

    #define STAGE(KT) do {                                                                  \
        STAGE_CHUNK(wave, KT);                                                              \
        if (wave < 2) STAGE_CHUNK(8 + wave, KT);                                            \
    } while (0)

    #define LOADB(KT) do {                                                                  \
        br[(KT)&1][0] = *(const s16x8*)(kvB + (size_t)((KT)*16 + wn*2 + 0)*512 + lane*8);   \
        br[(KT)&1][1] = *(const s16x8*)(kvB + (size_t)((KT)*16 + wn*2 + 1)*512 + lane*8);   \
    } while (0)

    #define NV1(KT) ((KT)==0?6:((KT)==1?8:((KT)==2?10:((KT)<=8?8:((KT)==9?7:6)))))
    #define NV2(KT) ((KT)==0?8:((KT)==1?10:((KT)==2?12:((KT)<=8?10:((KT)==9?8:6)))))

    #pragma unroll
    for (int mt = 0; mt < 5; ++mt)
        tl[mt] = *(const f32x4*)(tmf + (size_t)(Mbase + mt * 16 + l16) * 100 + 96);
    STAGE(0); STAGE(1); STAGE(2);
    LOADB(0); LOADB(1);

    #define GITER(KT) do {                                                                  \
        if ((KT) <= 10) {                                                                   \
            if (wave < 2) { asm volatile("s_waitcnt vmcnt(%0)" :: "i"(NV2(KT)) : "memory"); }\
            else          { asm volatile("s_waitcnt vmcnt(%0)" :: "i"(NV1(KT)) : "memory"); }\
            __builtin_amdgcn_s_barrier();                                                   \
            __builtin_amdgcn_sched_barrier(0);                                              \
        }                                                                                   \
        s16x8 af[5];                                                                        \
        _Pragma("unroll")                                                                   \
        for (int mt = 0; mt < 5; ++mt) {                                                    \
            f32x4 lo, hi;                                                                   \
            if ((KT) <= 10) {                                                               \
                int r_ = mt * 16 + l16; int sw_ = r_ & 7; int y0_ = kg * 2;                 \
                const char* bp_ = sb + ((KT)%3)*10240 + r_ * 128;                           \
                lo = *(const f32x4*)(bp_ + ((y0_ ^ sw_) << 4));                             \
                hi = *(const f32x4*)(bp_ + (((y0_+1) ^ sw_) << 4));                         \
            } else {                                                                        \
                lo = (kg == 0) ? tl[mt] : (f32x4){0.f,0.f,0.f,0.f};                         \
                hi = (f32x4){0.f,0.f,0.f,0.f};                                              \
            }                                                                               \
            u32x4 q_;                                                                       \
            q_.x = cvtpk(lo.x, lo.y); q_.y = cvtpk(lo.z, lo.w);                             \
            q_.z = cvtpk(hi.x, hi.y); q_.w = cvtpk(hi.z, hi.w);                             \
            af[mt] = __builtin_bit_cast(s16x8, q_);                                         \
        }                                                                                   \
        _Pragma("unroll")                                                                   \
        for (int mt = 0; mt < 5; ++mt) {                                                    \
            acc[mt][0] = __builtin_amdgcn_mfma_f32_16x16x32_bf16(af[mt], br[(KT)&1][0], acc[mt][0], 0, 0, 0); \
            acc[mt][1] = __builtin_amdgcn_mfma_f32_16x16x32_bf16(af[mt], br[(KT)&1][1], acc[mt][1], 0, 0, 0); \
        }                                                                                   \
        if ((KT) <= 10) {                                                                   \
            asm volatile("s_waitcnt lgkmcnt(0)" ::: "memory");                              \
            __builtin_amdgcn_s_barrier();                                                   \
            __builtin_amdgcn_sched_barrier(0);                                              \
            if ((KT) <= 7) STAGE((KT)+3);                                                   \
            if ((KT)+2 <= 11) LOADB((KT)+2);                                                \
        }                                                                                   \
    } while (0)

    GITER(0); GITER(1); GITER(2);  GITER(3);
    GITER(4); GITER(5); GITER(6);  GITER(7);
    GITER(8); GITER(9); GITER(10); GITER(11);
    #undef GITER
    #undef STAGE
    #undef STAGE_CHUNK
    #undef LOADB
    #undef NV1
    #undef NV2

    __syncthreads();

    const int rg4 = (lane >> 4) * 4;
    if (wn < 4) {
        #pragma unroll
        for (int mt = 0; mt < 5; ++mt) {
            const int r0 = mt * 16 + rg4;
            float w4v[4];
            #pragma unroll
            for (int i = 0; i < 4; ++i) w4v[i] = wgt[Mbase + r0 + i];
            #pragma unroll
            for (int nt = 0; nt < 2; ++nt) {
                const int c = wn * 32 + nt * 16 + l16;
                const float fb = kfb[c], bb = bk[c];
                #pragma unroll
                for (int i = 0; i < 4; ++i)
                    kls[(r0 + i) * 132 + c] = f2b(fmaf(acc[mt][nt][i] + fb, w4v[i], bb));
            }
        }
    } else {
        #pragma unroll
        for (int mt = 0; mt < 5; ++mt) {
            const int r0 = mt * 16 + rg4;
            float w4v[4];
            #pragma unroll
            for (int i = 0; i < 4; ++i) w4v[i] = wgt[Mbase + r0 + i];
            #pragma unroll
            for (int nt = 0; nt < 2; ++nt) {
                const int c = (wn - 4) * 32 + nt * 16 + l16;
                const float fb = vfb[c], bb = bv[c];
                #pragma unroll
                for (int i = 0; i < 4; ++i)
                    acc[mt][nt][i] = fmaf(acc[mt][nt][i] + fb, w4v[i], bb);
            }
        }
    }
    __syncthreads();

    const int lb = wave >> 1, h = wave & 1;
    const int brow = Bbase + lb;
    {
        const int flagv = *flagp;
        bool mybit = false;
        if (lane < NN) {
            if (flagv) mybit = ((const unsigned char*)maskp)[brow * NN + lane] != 0;
            else       mybit = ((const int*)maskp)[brow * NN + lane] != 0;
        }
        u64 bal = __ballot(mybit);
        u32 mb = (u32)(bal & 0xFFFFFull);
        const bool invalid = (mb == 0xFFFFFu);
        if (invalid) mb &= ~1u;
        if (h == 0 && lane == 0) flags[brow] = invalid ? 1 : 0;

        const int n = lane & 31;
        float s = -INFINITY;
        if (lane < 32 && n < NN) {
            const u16* kr = kls + (lb * NN + n) * 132 + h * 64;
            const u16* qr = Qg + (size_t)brow * 128 + h * 64;
            float d = 0.f;
            #pragma unroll
            for (int dc = 0; dc < 16; ++dc) {
                uint2 kw = *(const uint2*)(kr + dc * 4);
                uint2 qw = *(const uint2*)(qr + dc * 4);
                d = fmaf(blo(kw.x), blo(qw.x), d);  d = fmaf(bhi(kw.x), bhi(qw.x), d);
                d = fmaf(blo(kw.y), blo(qw.y), d);  d = fmaf(bhi(kw.y), bhi(qw.y), d);
            }
            s = ((mb >> n) & 1u) ? -INFINITY : d * 0.125f;
        }
        float mx = s;
        #pragma unroll
        for (int off = 16; off; off >>= 1) mx = fmaxf(mx, __shfl_xor(mx, off, 32));
        float e = (lane < 32 && n < NN) ? expf(s - mx) : 0.f;
        float sum = e;
        #pragma unroll
        for (int off = 16; off; off >>= 1) sum += __shfl_xor(sum, off, 32);
        if (lane < NN) p_lds[wave * NN + lane] = e / sum;
    }
    __syncthreads();

    if (wn >= 4) {
        #pragma unroll
        for (int mt = 0; mt < 5; ++mt) {
            const int r0 = mt * 16 + rg4;
            #pragma unroll
            for (int nt = 0; nt < 2; ++nt) {
                const int c = (wn - 4) * 32 + nt * 16 + l16;
                #pragma unroll
                for (int i = 0; i < 4; ++i)
                    kls[(r0 + i) * 132 + c] = f2b(acc[mt][nt][i]);
            }
        }
    }
    __syncthreads();

    {
        float cacc = 0.f;
        #pragma unroll
        for (int n2 = 0; n2 < NN; ++n2) {
            float pn = p_lds[wave * NN + n2];
            cacc = fmaf(pn, b2f(kls[(lb * NN + n2) * 132 + h * 64 + lane]), cacc);
        }
        ctxout[(size_t)brow * 128 + h * 64 + lane] = f2b(cacc);
    }
}

// generic small GEMM (used for Q only): C[M x 128] = A[M x 128] @ W^T + bias
#define GM_Q 0

template<int MODE>
__global__ __launch_bounds__(256) void gemm_small(
    const void* __restrict__ Asrc, const float* __restrict__ Asrc2,
    const u16* __restrict__ Bimg, const float* __restrict__ bias,
    const unsigned char* __restrict__ flags, void* __restrict__ outp)
{
    __shared__ u16 lA[64 * 72];
    __shared__ u16 lB[128 * 72];
    const int tid = threadIdx.x;
    const int Mbase = blockIdx.x * 64;
    const int lane = tid & 63, wave = tid >> 6;
    const int wm = wave >> 1, wn = wave & 1;
    const int row = tid >> 2, cg = tid & 3;

    f32x4 acc[2][4] = {};
    const size_t r = (size_t)(Mbase + row);

    for (int kt = 0; kt < 2; ++kt) {
        {
            const float* ap = (const float*)Asrc + r * 128 + kt * 64 + cg * 16;
            f32x4 x0 = *(const f32x4*)ap,       x1 = *(const f32x4*)(ap + 4);
            f32x4 x2 = *(const f32x4*)(ap + 8), x3 = *(const f32x4*)(ap + 12);
            *(uint4*)(&lA[row * 72 + cg * 16])     = make_uint4(pk2(x0.x,x0.y), pk2(x0.z,x0.w), pk2(x1.x,x1.y), pk2(x1.z,x1.w));
            *(uint4*)(&lA[row * 72 + cg * 16 + 8]) = make_uint4(pk2(x2.x,x2.y), pk2(x2.z,x2.w), pk2(x3.x,x3.y), pk2(x3.z,x3.w));
        }
        for (int c = wave; c < 18; c += 4) {
            const char* g = (const char*)Bimg + (size_t)kt * 18432 + c * 1024 + lane * 16;
            char* l = (char*)lB + c * 1024;
            __builtin_amdgcn_global_load_lds((const __attribute__((address_space(1))) u32*)g,
                                             (__attribute__((address_space(3))) u32*)l, 16, 0, 0);
        }
        __syncthreads();
        #pragma unroll
        for (int ks = 0; ks < 2; ++ks) {
            int kk = ks * 32 + (lane >> 4) * 8;
            s16x8 a[2], b[4];
            #pragma unroll
            for (int mt = 0; mt < 2; ++mt)
                a[mt] = *(const s16x8*)(&lA[(wm * 32 + mt * 16 + (lane & 15)) * 72 + kk]);
            #pragma unroll
            for (int nt = 0; nt < 4; ++nt)
                b[nt] = *(const s16x8*)(&lB[(wn * 64 + nt * 16 + (lane & 15)) * 72 + kk]);
            #pragma unroll
            for (int mt = 0; mt < 2; ++mt)
                #pragma unroll
                for (int nt = 0; nt < 4; ++nt)
                    acc[mt][nt] = __builtin_amdgcn_mfma_f32_16x16x32_bf16(a[mt], b[nt], acc[mt][nt], 0, 0, 0);
        }
        __syncthreads();
    }

    #pragma unroll
    for (int mt = 0; mt < 2; ++mt) {
        #pragma unroll
        for (int nt = 0; nt < 4; ++nt) {
            int colg = wn * 64 + nt * 16 + (lane & 15);
            float bb = bias[colg];
            #pragma unroll
            for (int i = 0; i < 4; ++i) {
                int rg = Mbase + wm * 32 + mt * 16 + (lane >> 4) * 4 + i;
                ((u16*)outp)[(size_t)rg * 128 + colg] = f2b(acc[mt][nt][i] + bb);
            }
        }
    }
}

// FUSED TAIL: out = W2 @ relu(W1 @ [relu(mask(Wo@ctx+bo)), src] + b1) + b2
__global__ __launch_bounds__(256) void gemm_tail(
    const u16* __restrict__ ctx, const float* __restrict__ src,
    const u16* __restrict__ woI, const u16* __restrict__ w1I, const u16* __restrict__ w2I,
    const float* __restrict__ bo, const float* __restrict__ b1, const float* __restrict__ b2,
    const unsigned char* __restrict__ flags, float* __restrict__ outp)
{
    __shared__ u16 lA[64 * 72];
    __shared__ u16 lB[128 * 72];
    __shared__ u16 s_a[64 * 136];
    const int tid = threadIdx.x;
    const int Mbase = blockIdx.x * 64;
    const int lane = tid & 63, wave = tid >> 6;
    const int wm = wave >> 1, wn = wave & 1;
    const int row = tid >> 2, cg = tid & 3;
    const size_t r = (size_t)(Mbase + row);

    #define STAGEB(IMG, KT) do {                                                            \
        for (int c_ = wave; c_ < 18; c_ += 4) {                                             \
            const char* g_ = (const char*)(IMG) + (size_t)(KT) * 18432 + c_ * 1024 + lane * 16; \
            char* l_ = (char*)lB + c_ * 1024;                                               \
            __builtin_amdgcn_global_load_lds((const __attribute__((address_space(1))) u32*)g_, \
                                             (__attribute__((address_space(3))) u32*)l_, 16, 0, 0); \
        }                                                                                   \
    } while (0)

    #define MFMA_STEP(ASRC, ASTRIDE, KOFF) do {                                             \
        _Pragma("unroll")                                                                   \
        for (int ks_ = 0; ks_ < 2; ++ks_) {                                                 \
            int kk_ = ks_ * 32 + (lane >> 4) * 8;                                           \
            s16x8 a_[2], b_[4];                                                             \
            _Pragma("unroll")                                                               \
            for (int mt_ = 0; mt_ < 2; ++mt_)                                               \
                a_[mt_] = *(const s16x8*)(&(ASRC)[(wm * 32 + mt_ * 16 + (lane & 15)) * (ASTRIDE) + (KOFF) + kk_]); \
            _Pragma("unroll")                                                               \
            for (int nt_ = 0; nt_ < 4; ++nt_)                                               \
                b_[nt_] = *(const s16x8*)(&lB[(wn * 64 + nt_ * 16 + (lane & 15)) * 72 + kk_]); \
            _Pragma("unroll")                                                               \
            for (int mt_ = 0; mt_ < 2; ++mt_)                                               \
                _Pragma("unroll")                                                           \
                for (int nt_ = 0; nt_ < 4; ++nt_)                                           \
                    acc[mt_][nt_] = __builtin_amdgcn_mfma_f32_16x16x32_bf16(a_[mt_], b_[nt_], acc[mt_][nt_], 0, 0, 0); \
        }                                                                                   \
    } while (0)

    f32x4 acc[2][4];

    // Phase 1: aout = relu(mask(Wo @ ctx + bo)) -> s_a
    #pragma unroll
    for (int mt = 0; mt < 2; ++mt)
        #pragma unroll
        for (int nt = 0; nt < 4; ++nt) acc[mt][nt] = (f32x4){0.f,0.f,0.f,0.f};

    for (int kt = 0; kt < 2; ++kt) {
        {
            const u16* ap = ctx + r * 128 + kt * 64 + cg * 16;
            *(uint4*)(&lA[row * 72 + cg * 16])     = *(const uint4*)ap;
            *(uint4*)(&lA[row * 72 + cg * 16 + 8]) = *(const uint4*)(ap + 8);
        }
        STAGEB(woI, kt);
        __syncthreads();
        MFMA_STEP(lA, 72, 0);
        __syncthreads();
    }
    #pragma unroll
    for (int mt = 0; mt < 2; ++mt) {
        #pragma unroll
        for (int nt = 0; nt < 4; ++nt) {
            int colg = wn * 64 + nt * 16 + (lane & 15);
            float bb = bo[colg];
            #pragma unroll
            for (int i = 0; i < 4; ++i) {
                int rl = wm * 32 + mt * 16 + (lane >> 4) * 4 + i;
                float val = acc[mt][nt][i] + bb;
                if (flags[Mbase + rl]) val = 0.f;
                s_a[rl * 136 + colg] = f2b(fmaxf(val, 0.f));
            }
        }
    }
    __syncthreads();

    // Phase 2: hmid = relu(W1 @ [aout(s_a), src] + b1) -> s_a
    #pragma unroll
    for (int mt = 0; mt < 2; ++mt)
        #pragma unroll
        for (int nt = 0; nt < 4; ++nt) acc[mt][nt] = (f32x4){0.f,0.f,0.f,0.f};

    for (int kt = 0; kt < 4; ++kt) {
        if (kt >= 2) {
            const float* ap = src + r * 128 + (kt - 2) * 64 + cg * 16;
            f32x4 x0 = *(const f32x4*)ap,       x1 = *(const f32x4*)(ap + 4);
            f32x4 x2 = *(const f32x4*)(ap + 8), x3 = *(const f32x4*)(ap + 12);
            *(uint4*)(&lA[row * 72 + cg * 16])     = make_uint4(pk2(x0.x,x0.y), pk2(x0.z,x0.w), pk2(x1.x,x1.y), pk2(x1.z,x1.w));
            *(uint4*)(&lA[row * 72 + cg * 16 + 8]) = make_uint4(pk2(x2.x,x2.y), pk2(x2.z,x2.w), pk2(x3.x,x3.y), pk2(x3.z,x3.w));
        }
        STAGEB(w1I, kt);
        __syncthreads();
        if (kt < 2) MFMA_STEP(s_a, 136, kt * 64);
        else        MFMA_STEP(lA, 72, 0);
        __syncthreads();
    }
    #pragma unroll
    for (int mt = 0; mt < 2; ++mt) {
        #pragma unroll
        for (int nt = 0; nt < 4; ++nt) {
            int colg = wn * 64 + nt * 16 + (lane & 15);
            float bb = b1[colg];
            #pragma unroll
            for (int i = 0; i < 4; ++i) {
                int rl = wm * 32 + mt * 16 + (lane >> 4) * 4 + i;
                s_a[rl * 136 + colg] = f2b(fmaxf(acc[mt][nt][i] + bb, 0.f));
            }
        }
    }
    __syncthreads();

    // Phase 3: out = W2 @ hmid + b2 -> global
    #pragma unroll
    for (int mt = 0; mt < 2; ++mt)
        #pragma unroll
        for (int nt = 0; nt < 4; ++nt) acc[mt][nt] = (f32x4){0.f,0.f,0.f,0.f};

    for (int kt = 0; kt < 2; ++kt) {
        STAGEB(w2I, kt);
        __syncthreads();
        MFMA_STEP(s_a, 136, kt * 64);
        __syncthreads();
    }
    #pragma unroll
    for (int mt = 0; mt < 2; ++mt) {
        #pragma unroll
        for (int nt = 0; nt < 4; ++nt) {
            int colg = wn * 64 + nt * 16 + (lane & 15);
            float bb = b2[colg];
            #pragma unroll
            for (int i = 0; i < 4; ++i) {
                int rg = Mbase + wm * 32 + mt * 16 + (lane >> 4) * 4 + i;
                outp[(size_t)rg * 128 + colg] = acc[mt][nt][i] + bb;
            }
        }
    }
    #undef STAGEB
    #undef MFMA_STEP
}

// ==================== tier-2: round-2 path (known-good) ====================

__global__ void prep_pack_r2(const float* __restrict__ wkt, const float* __restrict__ wvt,
                             const float* __restrict__ Wq, const float* __restrict__ Wo,
                             const float* __restrict__ W1, const float* __restrict__ W2,
                             u16* __restrict__ bpack, u32* __restrict__ wq2, u32* __restrict__ wo2,
                             u32* __restrict__ w12, u32* __restrict__ w22)
{
    const int id = blockIdx.x * 256 + threadIdx.x;
    if (id < 98304) {
        int kt = id >> 14;
        int o  = id & 16383;
        int n  = o >> 6;
        int kk = (o & 63) ^ ((n & 7) << 3);
        int k  = kt * 64 + kk;
        float v = 0.f;
        if (k < KD) v = (n < FF) ? wkt[k * FF + n] : wvt[k * FF + (n - FF)];
        bpack[id] = f2b(v);
    } else if (id < 106496) {
        int e = id - 98304; int j = e >> 6, tt = e & 63;
        wq2[e] = (u32)f2b(Wq[tt * FF + j]) | ((u32)f2b(Wq[(tt + 64) * FF + j]) << 16);
    } else if (id < 114688) {
        int e = id - 106496; int j = e >> 6, tt = e & 63;
        wo2[e] = (u32)f2b(Wo[tt * FF + j]) | ((u32)f2b(Wo[(tt + 64) * FF + j]) << 16);
    } else if (id < 131072) {
        int e = id - 114688; int j = e >> 6, tt = e & 63;
        w12[e] = (u32)f2b(W1[tt * 2 * FF + j]) | ((u32)f2b(W1[(tt + 64) * 2 * FF + j]) << 16);
    } else if (id < 139264) {
        int e = id - 131072; int j = e >> 6, tt = e & 63;
        w22[e] = (u32)f2b(W2[tt * FF + j]) | ((u32)f2b(W2[(tt + 64) * FF + j]) << 16);
    }
}

__global__ __launch_bounds__(512) void kv_gemm_r2(
    const float* __restrict__ nbr, const float* __restrict__ edg, const float* __restrict__ tmf,
    const float* __restrict__ wgt, const float* __restrict__ bk, const float* __restrict__ bv,
    const u16* __restrict__ bpack, const float* __restrict__ kfb, const float* __restrict__ vfb,
    u16* __restrict__ kvout)
{
    __shared__ u16 lA[128 * 64];
    __shared__ u16 lB[256 * 64];
    const int tid = threadIdx.x;
    const int Mbase = blockIdx.x * 128;
    const int lane = tid & 63, wave = tid >> 6;
    const int wm = wave >> 2, wn = wave & 3;

    f32x4 acc[4][4] = {};
    const int rq = tid >> 4;
    const int cq = tid & 15;

    for (int kt = 0; kt < 6; ++kt) {
        #pragma unroll
        for (int i = 0; i < 4; ++i) {
            int row = rq + i * 32;
            size_t r = (size_t)(Mbase + row);
            f32x4 v;
            if (kt < 2)       v = *(const f32x4*)(nbr + r * 128 + kt * 64 + cq * 4);
            else if (kt < 4)  v = *(const f32x4*)(edg + r * 128 + (kt - 2) * 64 + cq * 4);
            else if (kt == 4) v = *(const f32x4*)(tmf + r * 100 + cq * 4);
            else if (cq < 9)  v = *(const f32x4*)(tmf + r * 100 + 64 + cq * 4);
            else              v = (f32x4){0.f, 0.f, 0.f, 0.f};
            int off = row * 64 + ((cq * 4) ^ ((row & 7) << 3));
            *(uint2*)(&lA[off]) = make_uint2(pk2(v.x, v.y), pk2(v.z, v.w));
        }
        #pragma unroll
        for (int i = 0; i < 4; ++i) {
            int boff = wave * 4096 + i * 1024;
            const char* g = (const char*)bpack + (size_t)kt * 32768 + boff + lane * 16;
            char* l = (char*)lB + boff;
            __builtin_amdgcn_global_load_lds((const __attribute__((address_space(1))) u32*)g,
                                             (__attribute__((address_space(3))) u32*)l, 16, 0, 0);
        }
        __syncthreads();
        #pragma unroll
        for (int ks = 0; ks < 2; ++ks) {
            int kk = ks * 32 + (lane >> 4) * 8;
            s16x8 a[4], b[4];
            #pragma unroll
            for (int mt = 0; mt < 4; ++mt) {
                int m = wm * 64 + mt * 16 + (lane & 15);
                a[mt] = *(const s16x8*)(&lA[m * 64 + (kk ^ ((m & 7) << 3))]);
            }
            #pragma unroll
            for (int nt = 0; nt < 4; ++nt) {
                int n = wn * 64 + nt * 16 + (lane & 15);
                b[nt] = *(const s16x8*)(&lB[n * 64 + (kk ^ ((n & 7) << 3))]);
            }
            #pragma unroll
            for (int mt = 0; mt < 4; ++mt)
                #pragma unroll
                for (int nt = 0; nt < 4; ++nt)
                    acc[mt][nt] = __builtin_amdgcn_mfma_f32_16x16x32_bf16(a[mt], b[nt], acc[mt][nt], 0, 0, 0);
        }
        __syncthreads();
    }

    #pragma unroll
    for (int mt = 0; mt < 4; ++mt) {
        float w4[4];
        #pragma unroll
        for (int i = 0; i < 4; ++i)
            w4[i] = wgt[Mbase + wm * 64 + mt * 16 + (lane >> 4) * 4 + i];
        #pragma unroll
        for (int nt = 0; nt < 4; ++nt) {
            int c = wn * 64 + nt * 16 + (lane & 15);
            float fb   = (c < FF) ? kfb[c] : vfb[c - FF];
            float bias = (c < FF) ? bk[c]  : bv[c - FF];
            #pragma unroll
            for (int i = 0; i < 4; ++i) {
                int rr = Mbase + wm * 64 + mt * 16 + (lane >> 4) * 4 + i;
                float val = fmaf(acc[mt][nt][i] + fb, w4[i], bias);
                kvout[(size_t)rr * 256 + c] = f2b(val);
            }
        }
    }
}

__global__ __launch_bounds__(64) void gat_attn_r2(
    const float* __restrict__ src, const void* __restrict__ maskp,
    const float* __restrict__ bq, const float* __restrict__ bo,
    const float* __restrict__ b1, const float* __restrict__ b2,
    const u16* __restrict__ kv, const u32* __restrict__ wq2, const u32* __restrict__ wo2,
    const u32* __restrict__ w12, const u32* __restrict__ w22,
    const int* __restrict__ flagp, float* __restrict__ out)
{
    const int b = blockIdx.x, t = threadIdx.x;
    __shared__ u16 kls[NN * 132];
    __shared__ float s_src[FF], s_q[FF], s_ctx[FF], s_out[FF], s_h[FF];
    __shared__ float s_sc[2 * NN];

    const int flag = *flagp;
    bool mybit = false;
    if (t < NN) {
        if (flag) mybit = ((const unsigned char*)maskp)[b * NN + t] != 0;
        else      mybit = ((const int*)maskp)[b * NN + t] != 0;
    }
    u64 bal = __ballot(mybit);
    u32 mb = (u32)(bal & 0xFFFFFull);
    const bool invalid = (mb == 0xFFFFFu);
    if (invalid) mb &= ~1u;

    s_src[t] = src[(size_t)b * FF + t];
    s_src[t + 64] = src[(size_t)b * FF + 64 + t];

    float v0[NN], v1[NN];
    #pragma unroll
    for (int n = 0; n < NN; ++n) {
        const u16* row = kv + ((size_t)b * NN + n) * 256;
        kls[n * 132 + t]      = row[t];
        kls[n * 132 + 64 + t] = row[64 + t];
        v0[n] = b2f(row[128 + t]);
        v1[n] = b2f(row[192 + t]);
    }
    __syncthreads();

    {
        float q0 = bq[t], q1 = bq[64 + t];
        for (int j = 0; j < FF; ++j) {
            u32 u = wq2[j * 64 + t];
            float sj = s_src[j];
            q0 = fmaf(blo(u), sj, q0);
            q1 = fmaf(bhi(u), sj, q1);
        }
        s_q[t] = q0; s_q[64 + t] = q1;
    }
    __syncthreads();

    if (t < 2 * NN) {
        int h = t / NN, n = t - (t / NN) * NN;
        const u16* kr = kls + n * 132 + h * 64;
        const float* qr = s_q + h * 64;
        float s = 0.f;
        #pragma unroll
        for (int d = 0; d < 64; ++d) s = fmaf(qr[d], b2f(kr[d]), s);
        s *= 0.125f;
        s_sc[t] = ((mb >> n) & 1u) ? -INFINITY : s;
    }
    __syncthreads();
    if (t < 2) {
        float mx = -INFINITY;
        for (int n = 0; n < NN; ++n) mx = fmaxf(mx, s_sc[t * NN + n]);
        float e[NN]; float sum = 0.f;
        for (int n = 0; n < NN; ++n) { e[n] = expf(s_sc[t * NN + n] - mx); sum += e[n]; }
        float inv = 1.f / sum;
        for (int n = 0; n < NN; ++n) s_sc[t * NN + n] = e[n] * inv;
    }
    __syncthreads();

    {
        float c0 = 0.f, c1 = 0.f;
        #pragma unroll
        for (int n = 0; n < NN; ++n) {
            c0 = fmaf(s_sc[n],      v0[n], c0);
            c1 = fmaf(s_sc[NN + n], v1[n], c1);
        }
        s_ctx[t] = c0; s_ctx[64 + t] = c1;
    }
    __syncthreads();

    {
        float o0 = bo[t], o1 = bo[64 + t];
        for (int j = 0; j < FF; ++j) {
            u32 u = wo2[j * 64 + t];
            float cj = s_ctx[j];
            o0 = fmaf(blo(u), cj, o0);
            o1 = fmaf(bhi(u), cj, o1);
        }
        if (invalid) { o0 = 0.f; o1 = 0.f; }
        o0 = fmaxf(o0, 0.f); o1 = fmaxf(o1, 0.f);
        s_out[t] = o0; s_out[64 + t] = o1;
    }
    __syncthreads();

    {
        float h0 = b1[t], h1 = b1[64 + t];
        for (int j = 0; j < FF; ++j) {
            u32 u = w12[j * 64 + t];
            float xj = s_out[j];
            h0 = fmaf(blo(u), xj, h0);
            h1 = fmaf(bhi(u), xj, h1);
        }
        for (int j = 0; j < FF; ++j) {
            u32 u = w12[(FF + j) * 64 + t];
            float xj = s_src[j];
            h0 = fmaf(blo(u), xj, h0);
            h1 = fmaf(bhi(u), xj, h1);
        }
        h0 = fmaxf(h0, 0.f); h1 = fmaxf(h1, 0.f);
        s_h[t] = h0; s_h[64 + t] = h1;
    }
    __syncthreads();

    {
        float f0 = b2[t], f1 = b2[64 + t];
        for (int j = 0; j < FF; ++j) {
            u32 u = w22[j * 64 + t];
            float hj = s_h[j];
            f0 = fmaf(blo(u), hj, f0);
            f1 = fmaf(bhi(u), hj, f1);
        }
        out[(size_t)b * FF + t] = f0;
        out[(size_t)b * FF + 64 + t] = f1;
    }
}

// ==================== tier-3 fallback (round-1, known-good) ====================

#define FB_WKT  0
#define FB_WVT  (FB_WKT + KD*FF)
#define FB_KB   (FB_WVT + KD*FF)
#define FB_VB   (FB_KB + FF)
#define FB_WQT  (FB_VB + FF)
#define FB_WOT  (FB_WQT + FF*FF)
#define FB_W1T  (FB_WOT + FF*FF)
#define FB_W2T  (FB_W1T + 2*FF*FF)
#define FB_FLAG (FB_W2T + FF*FF)

__global__ void gat_prep_fb(const float* __restrict__ Wt, const float* __restrict__ bt,
                            const float* __restrict__ Wq, const float* __restrict__ Wk,
                            const float* __restrict__ Wv, const float* __restrict__ Wo,
                            const float* __restrict__ W1, const float* __restrict__ W2,
                            const u32* __restrict__ maskw, float* __restrict__ ws)
{
    const int blk = blockIdx.x;
    const int t = threadIdx.x;
    if (blk < KD) {
        __shared__ float col[FF];
        col[t] = Wt[t * KD + blk];
        __syncthreads();
        float ak = 0.f, av = 0.f;
        for (int j = 0; j < FF; ++j) {
            float c = col[j];
            ak = fmaf(Wk[t * FF + j], c, ak);
            av = fmaf(Wv[t * FF + j], c, av);
        }
        ws[FB_WKT + blk * FF + t] = ak;
        ws[FB_WVT + blk * FF + t] = av;
    } else if (blk == KD) {
        float ak = 0.f, av = 0.f;
        for (int j = 0; j < FF; ++j) {
            float c = bt[j];
            ak = fmaf(Wk[t * FF + j], c, ak);
            av = fmaf(Wv[t * FF + j], c, av);
        }
        ws[FB_KB + t] = ak;
        ws[FB_VB + t] = av;
    } else if (blk == KD + 1) {
        int any = 0;
        for (int i = t; i < 8192; i += 128) any |= (maskw[i] > 1u) ? 1 : 0;
        any = __any(any) ? 1 : 0;
        __shared__ int red[2];
        if ((t & 63) == 0) red[t >> 6] = any;
        __syncthreads();
        if (t == 0) ((int*)ws)[FB_FLAG] = (red[0] | red[1]) ? 1 : 0;
    } else {
        int id = (blk - (KD + 2)) * 128 + t;
        if (id < FF * FF) {
            int k = id >> 7, f = id & 127;
            ws[FB_WQT + id] = Wq[f * FF + k];
        } else if (id < 2 * FF * FF) {
            int e = id - FF * FF; int k = e >> 7, f = e & 127;
            ws[FB_WOT + e] = Wo[f * FF + k];
        } else if (id < 4 * FF * FF) {
            int e = id - 2 * FF * FF; int j = e >> 7, f = e & 127;
            ws[FB_W1T + e] = W1[f * (2 * FF) + j];
        } else if (id < 5 * FF * FF) {
            int e = id - 4 * FF * FF; int k = e >> 7, f = e & 127;
            ws[FB_W2T + e] = W2[f * FF + k];
        }
    }
}

__global__ __launch_bounds__(64) void gat_main_fb(
    const float* __restrict__ src, const float* __restrict__ nbr,
    const float* __restrict__ tmf, const float* __restrict__ edg,
    const void* __restrict__ maskp, const float* __restrict__ wgt,
    const float* __restrict__ bq, const float* __restrict__ bk,
    const float* __restrict__ bv, const float* __restrict__ bo,
    const float* __restrict__ b1, const float* __restrict__ b2,
    const float* __restrict__ ws, float* __restrict__ out)
{
    const int b = blockIdx.x;
    const int t = threadIdx.x;
    __shared__ __align__(16) float kin[KD * NN];
    __shared__ float s_src[FF], s_q[FF], s_ctx[FF], s_out[FF], s_h[FF];
    __shared__ float s_w[NN], s_sc[2 * NN];

    const int flag = ((const int*)ws)[FB_FLAG];
    bool mybit = false;
    if (t < NN) {
        if (flag) mybit = ((const unsigned char*)maskp)[b * NN + t] != 0;
        else      mybit = ((const int*)maskp)[b * NN + t] != 0;
    }
    u64 bal = __ballot(mybit);
    u32 mb = (u32)(bal & 0xFFFFFull);
    const bool invalid = (mb == 0xFFFFFu);
    if (invalid) mb &= ~1u;

    s_src[t] = src[(size_t)b * FF + t];
    s_src[t + 64] = src[(size_t)b * FF + 64 + t];
    if (t < NN) s_w[t] = wgt[(size_t)b * NN + t];

    for (int idx = t; idx < NN * FF; idx += 64) {
        int n = idx >> 7, j = idx & 127;
        kin[j * NN + n]         = nbr[((size_t)b * NN + n) * FF + j];
        kin[(128 + j) * NN + n] = edg[((size_t)b * NN + n) * EE + j];
    }
    for (int idx = t; idx < NN * TT; idx += 64) {
        int n = idx / TT, j = idx - n * TT;
        kin[(256 + j) * NN + n] = tmf[((size_t)b * NN + n) * TT + j];
    }
    __syncthreads();

    const float* wkt = ws + FB_WKT;
    const float* wvt = ws + FB_WVT;
    float ak0[NN], ak1[NN], av0[NN], av1[NN];
#pragma unroll
    for (int n = 0; n < NN; ++n) { ak0[n] = 0.f; ak1[n] = 0.f; av0[n] = 0.f; av1[n] = 0.f; }
    for (int k = 0; k < KD; ++k) {
        float wk0 = wkt[k * FF + t],      wk1 = wkt[k * FF + 64 + t];
        float wv0 = wvt[k * FF + t],      wv1 = wvt[k * FF + 64 + t];
        const float4* cp = (const float4*)(kin + k * NN);
        float4 ca = cp[0], cb = cp[1], cc = cp[2], cd = cp[3], ce = cp[4];
        const float c[NN] = { ca.x, ca.y, ca.z, ca.w,  cb.x, cb.y, cb.z, cb.w,
                              cc.x, cc.y, cc.z, cc.w,  cd.x, cd.y, cd.z, cd.w,
                              ce.x, ce.y, ce.z, ce.w };
#pragma unroll
        for (int n = 0; n < NN; ++n) {
            ak0[n] = fmaf(wk0, c[n], ak0[n]);
            ak1[n] = fmaf(wk1, c[n], ak1[n]);
            av0[n] = fmaf(wv0, c[n], av0[n]);
            av1[n] = fmaf(wv1, c[n], av1[n]);
        }
    }
    __syncthreads();

    float* kls = kin;
    float* vls = kin + NN * 129;
    {
        const float kb0 = ws[FB_KB + t], kb1 = ws[FB_KB + 64 + t];
        const float vb0 = ws[FB_VB + t], vb1 = ws[FB_VB + 64 + t];
        const float k0b = bk[t], k1b = bk[64 + t];
        const float v0b = bv[t], v1b = bv[64 + t];
#pragma unroll
        for (int n = 0; n < NN; ++n) {
            float wn = s_w[n];
            kls[n * 129 + t]      = fmaf(wn, ak0[n] + kb0, k0b);
            kls[n * 129 + 64 + t] = fmaf(wn, ak1[n] + kb1, k1b);
            vls[n * 129 + t]      = fmaf(wn, av0[n] + vb0, v0b);
            vls[n * 129 + 64 + t] = fmaf(wn, av1[n] + vb1, v1b);
        }
    }
    {
        const float* wqT = ws + FB_WQT;
        float q0 = bq[t], q1 = bq[64 + t];
        for (int j = 0; j < FF; ++j) {
            float sj = s_src[j];
            q0 = fmaf(wqT[j * FF + t], sj, q0);
            q1 = fmaf(wqT[j * FF + 64 + t], sj, q1);
        }
        s_q[t] = q0; s_q[64 + t] = q1;
    }
    __syncthreads();

    if (t < 2 * NN) {
        int h = t / NN, n = t - (t / NN) * NN;
        const float* kr = kls + n * 129 + h * 64;
        const float* qr = s_q + h * 64;
        float s = 0.f;
#pragma unroll
        for (int d = 0; d < 64; ++d) s = fmaf(qr[d], kr[d], s);
        s *= 0.125f;
        s_sc[t] = ((mb >> n) & 1u) ? -INFINITY : s;
    }
    __syncthreads();
    if (t < 2) {
        float mx = -INFINITY;
        for (int n = 0; n < NN; ++n) mx = fmaxf(mx, s_sc[t * NN + n]);
        float e[NN]; float sum = 0.f;
        for (int n = 0; n < NN; ++n) { e[n] = expf(s_sc[t * NN + n] - mx); sum += e[n]; }
        float inv = 1.f / sum;
        for (int n = 0; n < NN; ++n) s_sc[t * NN + n] = e[n] * inv;
    }
    __syncthreads();

    {
        float c0 = 0.f, c1 = 0.f;
#pragma unroll
        for (int n = 0; n < NN; ++n) {
            c0 = fmaf(s_sc[n],      vls[n * 129 + t],      c0);
            c1 = fmaf(s_sc[NN + n], vls[n * 129 + 64 + t], c1);
        }
        s_ctx[t] = c0; s_ctx[64 + t] = c1;
    }
    __syncthreads();

    {
        const float* woT = ws + FB_WOT;
        float o0 = bo[t], o1 = bo[64 + t];
        for (int j = 0; j < FF; ++j) {
            float cj = s_ctx[j];
            o0 = fmaf(woT[j * FF + t], cj, o0);
            o1 = fmaf(woT[j * FF + 64 + t], cj, o1);
        }
        if (invalid) { o0 = 0.f; o1 = 0.f; }
        o0 = fmaxf(o0, 0.f); o1 = fmaxf(o1, 0.f);
        s_out[t] = o0; s_out[64 + t] = o1;
    }
    __syncthreads();

    {
        const float* w1T = ws + FB_W1T;
        float h0 = b1[t], h1 = b1[64 + t];
        for (int j = 0; j < FF; ++j) {
            float xj = s_out[j];
            h0 = fmaf(w1T[j * FF + t], xj, h0);
            h1 = fmaf(w1T[j * FF + 64 + t], xj, h1);
        }
        for (int j = 0; j < FF; ++j) {
            float xj = s_src[j];
            h0 = fmaf(w1T[(FF + j) * FF + t], xj, h0);
            h1 = fmaf(w1T[(FF + j) * FF + 64 + t], xj, h1);
        }
        h0 = fmaxf(h0, 0.f); h1 = fmaxf(h1, 0.f);
        s_h[t] = h0; s_h[64 + t] = h1;
    }
    __syncthreads();

    {
        const float* w2T = ws + FB_W2T;
        float f0 = b2[t], f1 = b2[64 + t];
        for (int j = 0; j < FF; ++j) {
            float hj = s_h[j];
            f0 = fmaf(w2T[j * FF + t], hj, f0);
            f1 = fmaf(w2T[j * FF + 64 + t], hj, f1);
        }
        out[(size_t)b * FF + t] = f0;
        out[(size_t)b * FF + 64 + t] = f1;
    }
}

// ==================== host ====================

extern "C" void kernel_launch(void* const* d_in, const int* in_sizes, int n_in,
                              void* d_out, int out_size, void* d_ws, size_t ws_size,
                              hipStream_t stream)
{
    const float* src = (const float*)d_in[0];
    const float* nbr = (const float*)d_in[1];
    const float* tmf = (const float*)d_in[2];
    const float* edg = (const float*)d_in[3];
    const void*  msk = d_in[4];
    const float* wgt = (const float*)d_in[5];
    const float* Wt  = (const float*)d_in[6];
    const float* bt  = (const float*)d_in[7];
    const float* Wq  = (const float*)d_in[8];
    const float* bq  = (const float*)d_in[9];
    const float* Wk  = (const float*)d_in[10];
    const float* bk  = (const float*)d_in[11];
    const float* Wv  = (const float*)d_in[12];
    const float* bv  = (const float*)d_in[13];
    const float* Wo  = (const float*)d_in[14];
    const float* bo  = (const float*)d_in[15];
    const float* W1  = (const float*)d_in[16];
    const float* b1  = (const float*)d_in[17];
    const float* W2  = (const float*)d_in[18];
    const float* b2  = (const float*)d_in[19];

    const int B = in_sizes[0] / FF;
    const size_t M = (size_t)B * NN;

    // tier-1 layout (bytes)
    size_t o1 = 0;
    size_t t1_qa   = o1; o1 += (size_t)B * 256;   // Q bf16
    size_t t1_ch   = o1; o1 += (size_t)B * 256;   // ctx bf16
    size_t t1_kvB  = o1; o1 += 393216;            // frag-major B image
    size_t t1_wqI  = o1; o1 += 36864;
    size_t t1_woI  = o1; o1 += 36864;
    size_t t1_w1I  = o1; o1 += 73728;
    size_t t1_w2I  = o1; o1 += 36864;
    size_t t1_wkt  = o1; o1 += (size_t)KD * FF * 4;
    size_t t1_wvt  = o1; o1 += (size_t)KD * FF * 4;
    size_t t1_kfb  = o1; o1 += 512;
    size_t t1_vfb  = o1; o1 += 512;
    size_t t1_flg  = o1; o1 += (size_t)B;         // invalid flags
    o1 = (o1 + 255) & ~(size_t)255;
    size_t t1_flag = o1; o1 += 64;
    const size_t need1 = o1;

    // tier-2 layout (bytes)
    size_t o2 = 0;
    size_t t2_kv    = o2; o2 += M * 512;
    size_t t2_bpack = o2; o2 += 98304ull * 2;
    size_t t2_wkt   = o2; o2 += (size_t)KD * FF * 4;
    size_t t2_wvt   = o2; o2 += (size_t)KD * FF * 4;
    size_t t2_kfb   = o2; o2 += 512;
    size_t t2_vfb   = o2; o2 += 512;
    size_t t2_wq2   = o2; o2 += 32768;
    size_t t2_wo2   = o2; o2 += 32768;
    size_t t2_w12   = o2; o2 += 65536;
    size_t t2_w22   = o2; o2 += 32768;
    size_t t2_flag  = o2; o2 += 64;
    const size_t need2 = o2;

    char* w = (char*)d_ws;

    if (ws_size >= need1 && (B % 64) == 0) {
        u16*   qa    = (u16*)(w + t1_qa);
        u16*   ch    = (u16*)(w + t1_ch);
        u16*   kvB   = (u16*)(w + t1_kvB);
        u16*   wqI   = (u16*)(w + t1_wqI);
        u16*   woI   = (u16*)(w + t1_woI);
        u16*   w1I   = (u16*)(w + t1_w1I);
        u16*   w2I   = (u16*)(w + t1_w2I);
        float* wktp  = (float*)(w + t1_wkt);
        float* wvtp  = (float*)(w + t1_wvt);
        float* kfb   = (float*)(w + t1_kfb);
        float* vfb   = (float*)(w + t1_vfb);
        unsigned char* flg = (unsigned char*)(w + t1_flg);
        int*   flagp = (int*)(w + t1_flag);

        prep_fuse<<<dim3(KD + 2), dim3(128), 0, stream>>>(Wt, bt, Wk, Wv,
            (const u32*)msk, wktp, wvtp, kfb, vfb, flagp);
        prep_pack_v4<<<dim3(1128), dim3(256), 0, stream>>>(wktp, wvtp, Wq, Wo, W1, W2,
            kvB, wqI, woI, w1I, w2I);
        gemm_small<GM_Q><<<dim3(B / 64), dim3(256), 0, stream>>>(
            (const void*)src, nullptr, wqI, bq, nullptr, (void*)qa);
        kv_attn_fused7<<<dim3(B / 4), dim3(512), 0, stream>>>(
            nbr, edg, tmf, wgt, bk, bv, kvB, kfb, vfb, qa, msk, flagp, ch, flg);
        gemm_tail<<<dim3(B / 64), dim3(256), 0, stream>>>(
            ch, src, woI, w1I, w2I, bo, b1, b2, flg, (float*)d_out);
    } else if (ws_size >= need2 && (M % 128) == 0) {
        u16*   kvp   = (u16*)(w + t2_kv);
        u16*   bpack = (u16*)(w + t2_bpack);
        float* wktp  = (float*)(w + t2_wkt);
        float* wvtp  = (float*)(w + t2_wvt);
        float* kfb   = (float*)(w + t2_kfb);
        float* vfb   = (float*)(w + t2_vfb);
        u32*   wq2   = (u32*)(w + t2_wq2);
        u32*   wo2   = (u32*)(w + t2_wo2);
        u32*   w12   = (u32*)(w + t2_w12);
        u32*   w22   = (u32*)(w + t2_w22);
        int*   flagp = (int*)(w + t2_flag);

        prep_fuse<<<dim3(KD + 2), dim3(128), 0, stream>>>(Wt, bt, Wk, Wv,
            (const u32*)msk, wktp, wvtp, kfb, vfb, flagp);
        prep_pack_r2<<<dim3(544), dim3(256), 0, stream>>>(wktp, wvtp, Wq, Wo, W1, W2,
            bpack, wq2, wo2, w12, w22);
        kv_gemm_r2<<<dim3((int)(M / 128)), dim3(512), 0, stream>>>(
            nbr, edg, tmf, wgt, bk, bv, bpack, kfb, vfb, kvp);
        gat_attn_r2<<<dim3(B), dim3(64), 0, stream>>>(
            src, msk, bq, bo, b1, b2, kvp, wq2, wo2, w12, w22, flagp, (float*)d_out);
    } else {
        float* ws = (float*)d_ws;
        gat_prep_fb<<<dim3(KD + 2 + 640), dim3(128), 0, stream>>>(
            Wt, bt, Wq, Wk, Wv, Wo, W1, W2, (const u32*)msk, ws);
        gat_main_fb<<<dim3(B), dim3(64), 0, stream>>>(
            src, nbr, tmf, edg, msk, wgt, bq, bk, bv, bo, b1, b2, ws, (float*)d_out);
    }
}